// Round 1
// baseline (2078.717 us; speedup 1.0000x reference)
//
#include <hip/hip_runtime.h>

#define BATCH   4
#define SEQ     2048
#define D_MODEL 1024
#define HEADS   16
#define HEAD_DIM 64

// ---------------------------------------------------------------------------
// fp32 tiled GEMM: C[M,N] = A[M,K] @ B[K,N].  64x64 block tile, BK=16,
// 256 threads, 4x4 micro-tile per thread. LDS padded to 68 floats/row:
// all hot ds_read_b128 patterns are <=2-way bank aliased (free on gfx950).
// ---------------------------------------------------------------------------
__global__ __launch_bounds__(256) void gemm_f32(
    const float* __restrict__ A, const float* __restrict__ B,
    float* __restrict__ C, int M, int N, int K)
{
    __shared__ float As[16][68];   // transposed: As[k][m]
    __shared__ float Bs[16][68];   // natural:    Bs[k][n]

    const int t  = threadIdx.x;
    const int tx = t & 15;         // col group (4 cols)
    const int ty = t >> 4;         // row group (4 rows)
    const int m0 = blockIdx.y * 64;
    const int n0 = blockIdx.x * 64;

    const int la_m = t >> 2;           // 0..63
    const int la_k = (t & 3) << 2;     // 0,4,8,12
    const int lb_k = t >> 4;           // 0..15
    const int lb_n = (t & 15) << 2;    // 0..60

    float acc[4][4] = {{0.f, 0.f, 0.f, 0.f}, {0.f, 0.f, 0.f, 0.f},
                       {0.f, 0.f, 0.f, 0.f}, {0.f, 0.f, 0.f, 0.f}};

    for (int k0 = 0; k0 < K; k0 += 16) {
        float4 av = *(const float4*)(A + (size_t)(m0 + la_m) * K + k0 + la_k);
        float4 bv = *(const float4*)(B + (size_t)(k0 + lb_k) * N + n0 + lb_n);
        As[la_k + 0][la_m] = av.x;
        As[la_k + 1][la_m] = av.y;
        As[la_k + 2][la_m] = av.z;
        As[la_k + 3][la_m] = av.w;
        *(float4*)(&Bs[lb_k][lb_n]) = bv;
        __syncthreads();
#pragma unroll
        for (int kk = 0; kk < 16; ++kk) {
            float4 a = *(const float4*)(&As[kk][ty << 2]);
            float4 b = *(const float4*)(&Bs[kk][tx << 2]);
            const float ar[4] = {a.x, a.y, a.z, a.w};
            const float br[4] = {b.x, b.y, b.z, b.w};
#pragma unroll
            for (int i = 0; i < 4; ++i)
#pragma unroll
                for (int j = 0; j < 4; ++j)
                    acc[i][j] += ar[i] * br[j];
        }
        __syncthreads();
    }
#pragma unroll
    for (int i = 0; i < 4; ++i) {
        float4 ov = make_float4(acc[i][0], acc[i][1], acc[i][2], acc[i][3]);
        *(float4*)(C + (size_t)(m0 + (ty << 2) + i) * N + n0 + (tx << 2)) = ov;
    }
}

// ---------------------------------------------------------------------------
// Flash-style fused attention, fp32.
// One block = one (b, h, 64-row Q tile). 256 threads, thread owns a 4x4
// patch of S/P (rows 4*r4+i, cols 4*c4+j) and the matching 4x4 patch of O
// (rows 4*r4+i, head-dims 4*c4+j). Online softmax state (m,l) per row lives
// replicated in the 16 threads of each row group; combined via 16-lane
// __shfl_xor (all within one wave).
// K tile is staged TRANSPOSED (Kt[d][c]) so the S-compute inner reads are
// row-contiguous b128 (<=2-way). After S is in registers the Kt region is
// reused to hold P (keeps static LDS at 52 KB < 64 KB -> 3 blocks/CU).
// ---------------------------------------------------------------------------
__global__ __launch_bounds__(256) void flash_attn(
    const float* __restrict__ Q, const float* __restrict__ K,
    const float* __restrict__ V, float* __restrict__ O)
{
    __shared__ float Qs[64][68];     // Qs[m][d]
    __shared__ float KtPs[64][68];   // Kt[d][c] during S; P[m][c] during PV
    __shared__ float Vs[64][68];     // Vs[c][d]

    const int t  = threadIdx.x;
    const int r4 = t >> 4;           // 0..15 row quad
    const int c4 = t & 15;           // 0..15 col quad
    const int b  = blockIdx.z;
    const int h  = blockIdx.y;
    const int q0 = blockIdx.x * 64;
    const size_t base = ((size_t)b * SEQ) * D_MODEL + (size_t)h * HEAD_DIM;

    const int lr = t >> 2;           // 0..63 load row
    const int lc = (t & 3) << 4;     // 0,16,32,48 load col base

    // Load Q tile (persistent across k-tiles)
#pragma unroll
    for (int j = 0; j < 4; ++j) {
        float4 qv = *(const float4*)(Q + base + (size_t)(q0 + lr) * D_MODEL + lc + (j << 2));
        *(float4*)(&Qs[lr][lc + (j << 2)]) = qv;
    }

    float o[4][4];
    float m_r[4], l_r[4];
#pragma unroll
    for (int i = 0; i < 4; ++i) {
        m_r[i] = -3.0e38f;
        l_r[i] = 0.f;
#pragma unroll
        for (int j = 0; j < 4; ++j) o[i][j] = 0.f;
    }

    for (int k0 = 0; k0 < SEQ; k0 += 64) {
        __syncthreads();  // prior-iter PV reads (and iter-0 Qs writes) done

        // Stage K (transposed) and V tiles
#pragma unroll
        for (int j = 0; j < 4; ++j) {
            float4 kv = *(const float4*)(K + base + (size_t)(k0 + lr) * D_MODEL + lc + (j << 2));
            KtPs[lc + (j << 2) + 0][lr] = kv.x;
            KtPs[lc + (j << 2) + 1][lr] = kv.y;
            KtPs[lc + (j << 2) + 2][lr] = kv.z;
            KtPs[lc + (j << 2) + 3][lr] = kv.w;
            float4 vv = *(const float4*)(V + base + (size_t)(k0 + lr) * D_MODEL + lc + (j << 2));
            *(float4*)(&Vs[lr][lc + (j << 2)]) = vv;
        }
        __syncthreads();

        // S[4r4+i][4c4+j] = sum_d Qs[row][d] * Kt[d][col]
        float acc[4][4] = {{0.f, 0.f, 0.f, 0.f}, {0.f, 0.f, 0.f, 0.f},
                           {0.f, 0.f, 0.f, 0.f}, {0.f, 0.f, 0.f, 0.f}};
#pragma unroll
        for (int d4 = 0; d4 < 16; ++d4) {
            float4 qv[4], kt[4];
#pragma unroll
            for (int i = 0; i < 4; ++i)
                qv[i] = *(const float4*)(&Qs[(r4 << 2) + i][d4 << 2]);
#pragma unroll
            for (int e = 0; e < 4; ++e)
                kt[e] = *(const float4*)(&KtPs[(d4 << 2) + e][c4 << 2]);
#pragma unroll
            for (int i = 0; i < 4; ++i) {
                const float qa[4] = {qv[i].x, qv[i].y, qv[i].z, qv[i].w};
#pragma unroll
                for (int e = 0; e < 4; ++e) {
                    const float kr[4] = {kt[e].x, kt[e].y, kt[e].z, kt[e].w};
#pragma unroll
                    for (int j = 0; j < 4; ++j)
                        acc[i][j] += qa[e] * kr[j];
                }
            }
        }
        __syncthreads();  // all Kt reads done; region becomes P storage

        // Online softmax on the 4x4 patch (scale = 1/sqrt(64) = 0.125)
#pragma unroll
        for (int i = 0; i < 4; ++i) {
            float mx = -3.0e38f;
#pragma unroll
            for (int j = 0; j < 4; ++j) {
                acc[i][j] *= 0.125f;
                mx = fmaxf(mx, acc[i][j]);
            }
#pragma unroll
            for (int off = 1; off < 16; off <<= 1)
                mx = fmaxf(mx, __shfl_xor(mx, off, 64));
            const float nm    = fmaxf(m_r[i], mx);
            const float alpha = __expf(m_r[i] - nm);
            m_r[i] = nm;
            float s = 0.f;
#pragma unroll
            for (int j = 0; j < 4; ++j) {
                const float p = __expf(acc[i][j] - nm);
                acc[i][j] = p;
                s += p;
            }
#pragma unroll
            for (int off = 1; off < 16; off <<= 1)
                s += __shfl_xor(s, off, 64);
            l_r[i] = alpha * l_r[i] + s;
#pragma unroll
            for (int j = 0; j < 4; ++j) o[i][j] *= alpha;
        }
        // Write P patch
#pragma unroll
        for (int i = 0; i < 4; ++i) {
            float4 pv = make_float4(acc[i][0], acc[i][1], acc[i][2], acc[i][3]);
            *(float4*)(&KtPs[(r4 << 2) + i][c4 << 2]) = pv;
        }
        __syncthreads();  // P complete

        // O[4r4+i][4c4+j] += sum_c P[row][c] * Vs[c][dim]
#pragma unroll
        for (int cq = 0; cq < 16; ++cq) {
            float4 pv[4], vv[4];
#pragma unroll
            for (int i = 0; i < 4; ++i)
                pv[i] = *(const float4*)(&KtPs[(r4 << 2) + i][cq << 2]);
#pragma unroll
            for (int e = 0; e < 4; ++e)
                vv[e] = *(const float4*)(&Vs[(cq << 2) + e][c4 << 2]);
#pragma unroll
            for (int i = 0; i < 4; ++i) {
                const float pa[4] = {pv[i].x, pv[i].y, pv[i].z, pv[i].w};
#pragma unroll
                for (int e = 0; e < 4; ++e) {
                    const float vr[4] = {vv[e].x, vv[e].y, vv[e].z, vv[e].w};
#pragma unroll
                    for (int j = 0; j < 4; ++j)
                        o[i][j] += pa[e] * vr[j];
                }
            }
        }
    }

    // Epilogue: O /= l, write [b, s, h*64 + d] (== concat layout)
#pragma unroll
    for (int i = 0; i < 4; ++i) {
        const float inv = 1.0f / l_r[i];
        float4 ov = make_float4(o[i][0] * inv, o[i][1] * inv,
                                o[i][2] * inv, o[i][3] * inv);
        *(float4*)(O + base + (size_t)(q0 + (r4 << 2) + i) * D_MODEL + (c4 << 2)) = ov;
    }
}

// ---------------------------------------------------------------------------
extern "C" void kernel_launch(void* const* d_in, const int* in_sizes, int n_in,
                              void* d_out, int out_size, void* d_ws, size_t ws_size,
                              hipStream_t stream) {
    const float* x  = (const float*)d_in[0];
    const float* Wq = (const float*)d_in[1];
    const float* Wk = (const float*)d_in[2];
    const float* Wv = (const float*)d_in[3];
    const float* Wo = (const float*)d_in[4];
    float* out = (float*)d_out;

    const int M = BATCH * SEQ;                    // 8192
    const size_t elems = (size_t)M * D_MODEL;     // 8.4M floats = 32 MB
    float* Q    = (float*)d_ws;
    float* K    = Q + elems;
    float* V    = K + elems;
    float* attn = V + elems;                      // total ws use: 128 MB

    dim3 blk(256);
    dim3 ggrid(D_MODEL / 64, M / 64);             // 16 x 128 = 2048 blocks

    hipLaunchKernelGGL(gemm_f32, ggrid, blk, 0, stream, x, Wq, Q, M, D_MODEL, D_MODEL);
    hipLaunchKernelGGL(gemm_f32, ggrid, blk, 0, stream, x, Wk, K, M, D_MODEL, D_MODEL);
    hipLaunchKernelGGL(gemm_f32, ggrid, blk, 0, stream, x, Wv, V, M, D_MODEL, D_MODEL);

    dim3 fgrid(SEQ / 64, HEADS, BATCH);           // 32 x 16 x 4 = 2048 blocks
    hipLaunchKernelGGL(flash_attn, fgrid, blk, 0, stream, Q, K, V, attn);

    hipLaunchKernelGGL(gemm_f32, ggrid, blk, 0, stream, attn, Wo, out, M, D_MODEL, D_MODEL);
}

// Round 2
// 629.947 us; speedup vs baseline: 3.2998x; 3.2998x over previous
//
#include <hip/hip_runtime.h>

#define BATCH   4
#define SEQ     2048
#define DM      1024
#define HEADS   16
#define HD      64
#define M_TOK   (BATCH * SEQ)   // 8192

typedef __attribute__((ext_vector_type(8))) short  short8;
typedef __attribute__((ext_vector_type(4))) float  f32x4;

__device__ __forceinline__ unsigned short f2bf(float x) {
    union { float f; unsigned int u; } v; v.f = x;
    unsigned int r = v.u + 0x7fffu + ((v.u >> 16) & 1u);
    return (unsigned short)(r >> 16);
}
__device__ __forceinline__ float bf2f(unsigned short h) {
    union { unsigned int u; float f; } v; v.u = ((unsigned int)h) << 16;
    return v.f;
}

// ---------------------------------------------------------------------------
// x -> hi/lo bf16 split (elementwise)
// ---------------------------------------------------------------------------
__global__ __launch_bounds__(256) void split_cast(
    const float* __restrict__ x, unsigned short* __restrict__ hi,
    unsigned short* __restrict__ lo)
{
    const int i = (blockIdx.x * 256 + threadIdx.x) * 8;
    float4 a = *(const float4*)(x + i);
    float4 b = *(const float4*)(x + i + 4);
    float v[8] = {a.x, a.y, a.z, a.w, b.x, b.y, b.z, b.w};
    unsigned short hb[8], lb[8];
#pragma unroll
    for (int j = 0; j < 8; ++j) {
        hb[j] = f2bf(v[j]);
        lb[j] = f2bf(v[j] - bf2f(hb[j]));
    }
    *(float4*)(hi + i) = *(float4*)hb;
    *(float4*)(lo + i) = *(float4*)lb;
}

// ---------------------------------------------------------------------------
// Weight transpose (+optional split): W[K][N] fp32 -> Wt[N][K] bf16 (hi[,lo])
// 64x64 tile via LDS.
// ---------------------------------------------------------------------------
template<int SPLIT>
__global__ __launch_bounds__(256) void wtrans(
    const float* __restrict__ W, unsigned short* __restrict__ Th_out,
    unsigned short* __restrict__ Tl_out)
{
    __shared__ unsigned short Th[64][72];
    __shared__ unsigned short Tl[SPLIT ? 64 : 1][72];
    const int t  = threadIdx.x;
    const int n0 = blockIdx.x * 64, k0 = blockIdx.y * 64;
    const int kr = t >> 2, cg = (t & 3) << 4;
#pragma unroll
    for (int jj = 0; jj < 16; jj += 4) {
        float4 wv = *(const float4*)(W + (size_t)(k0 + kr) * DM + n0 + cg + jj);
        float vv[4] = {wv.x, wv.y, wv.z, wv.w};
#pragma unroll
        for (int j = 0; j < 4; ++j) {
            unsigned short h = f2bf(vv[j]);
            Th[cg + jj + j][kr] = h;
            if (SPLIT) Tl[cg + jj + j][kr] = f2bf(vv[j] - bf2f(h));
        }
    }
    __syncthreads();
    const int nr = t >> 2, kg = (t & 3) << 4;
    size_t go = (size_t)(n0 + nr) * DM + k0 + kg;
    *(float4*)(Th_out + go)     = *(float4*)&Th[nr][kg];
    *(float4*)(Th_out + go + 8) = *(float4*)&Th[nr][kg + 8];
    if (SPLIT) {
        *(float4*)(Tl_out + go)     = *(float4*)&Tl[nr][kg];
        *(float4*)(Tl_out + go + 8) = *(float4*)&Tl[nr][kg + 8];
    }
}

// ---------------------------------------------------------------------------
// MFMA GEMM: C[M,N] = A[M,K] @ Bt[N,K]^T, bf16 inputs (optionally hi/lo split
// 3-pass), fp32 accumulate. Tile 128x128, BK=32, 256 threads = 4 waves in a
// 2x2 wave grid, each wave 4x4 MFMA tiles of 16x16x32.
// EPI: 0 = fp32 C; 1 = split bf16 (O0=hi, O1=lo); 2 = per-head transposed V
//      (O0 = Vt[b][h][d][s] bf16).
// LDS pitch 40 ushort = 80 B: rows 16B-aligned, frag reads uniform 2-way.
// ---------------------------------------------------------------------------
template<int PASSES, int EPI>
__global__ __launch_bounds__(256) void gemm_bt(
    const unsigned short* __restrict__ Ah, const unsigned short* __restrict__ Al,
    const unsigned short* __restrict__ Bh, const unsigned short* __restrict__ Bl,
    void* __restrict__ O0, void* __restrict__ O1, int M, int N, int K)
{
    __shared__ unsigned short As_h[128][40];
    __shared__ unsigned short Bs_h[128][40];
    __shared__ unsigned short As_l[PASSES == 3 ? 128 : 1][40];
    __shared__ unsigned short Bs_l[PASSES == 3 ? 128 : 1][40];

    const int t = threadIdx.x;
    const int w = t >> 6, lane = t & 63, quad = lane >> 4, l15 = lane & 15;
    const int wm = w >> 1, wn = w & 1;
    const int m0 = blockIdx.y * 128, n0 = blockIdx.x * 128;
    const int srow = t >> 1, scol = (t & 1) << 4;   // 128 rows x 32 cols staging

    f32x4 acc[4][4];
#pragma unroll
    for (int mt = 0; mt < 4; ++mt)
#pragma unroll
        for (int nt = 0; nt < 4; ++nt)
#pragma unroll
            for (int r = 0; r < 4; ++r) acc[mt][nt][r] = 0.f;

    for (int k0 = 0; k0 < K; k0 += 32) {
        const size_t ga = (size_t)(m0 + srow) * K + k0 + scol;
        const size_t gb = (size_t)(n0 + srow) * K + k0 + scol;
        *(float4*)&As_h[srow][scol]     = *(const float4*)(Ah + ga);
        *(float4*)&As_h[srow][scol + 8] = *(const float4*)(Ah + ga + 8);
        *(float4*)&Bs_h[srow][scol]     = *(const float4*)(Bh + gb);
        *(float4*)&Bs_h[srow][scol + 8] = *(const float4*)(Bh + gb + 8);
        if (PASSES == 3) {
            *(float4*)&As_l[srow][scol]     = *(const float4*)(Al + ga);
            *(float4*)&As_l[srow][scol + 8] = *(const float4*)(Al + ga + 8);
            *(float4*)&Bs_l[srow][scol]     = *(const float4*)(Bl + gb);
            *(float4*)&Bs_l[srow][scol + 8] = *(const float4*)(Bl + gb + 8);
        }
        __syncthreads();

        short8 aH[4], bH[4], aL[4], bL[4];
#pragma unroll
        for (int mt = 0; mt < 4; ++mt) {
            aH[mt] = *(const short8*)&As_h[wm * 64 + mt * 16 + l15][quad * 8];
            if (PASSES == 3)
                aL[mt] = *(const short8*)&As_l[wm * 64 + mt * 16 + l15][quad * 8];
        }
#pragma unroll
        for (int nt = 0; nt < 4; ++nt) {
            bH[nt] = *(const short8*)&Bs_h[wn * 64 + nt * 16 + l15][quad * 8];
            if (PASSES == 3)
                bL[nt] = *(const short8*)&Bs_l[wn * 64 + nt * 16 + l15][quad * 8];
        }
#pragma unroll
        for (int mt = 0; mt < 4; ++mt)
#pragma unroll
            for (int nt = 0; nt < 4; ++nt) {
                acc[mt][nt] = __builtin_amdgcn_mfma_f32_16x16x32_bf16(
                    aH[mt], bH[nt], acc[mt][nt], 0, 0, 0);
                if (PASSES == 3) {
                    acc[mt][nt] = __builtin_amdgcn_mfma_f32_16x16x32_bf16(
                        aH[mt], bL[nt], acc[mt][nt], 0, 0, 0);
                    acc[mt][nt] = __builtin_amdgcn_mfma_f32_16x16x32_bf16(
                        aL[mt], bH[nt], acc[mt][nt], 0, 0, 0);
                }
            }
        __syncthreads();
    }

    // Epilogue. C/D layout: col = lane&15, row = quad*4 + reg.
#pragma unroll
    for (int mt = 0; mt < 4; ++mt)
#pragma unroll
        for (int nt = 0; nt < 4; ++nt) {
            const int row0 = m0 + wm * 64 + mt * 16 + quad * 4;
            const int col  = n0 + wn * 64 + nt * 16 + l15;
            if (EPI == 0) {
#pragma unroll
                for (int r = 0; r < 4; ++r)
                    ((float*)O0)[(size_t)(row0 + r) * N + col] = acc[mt][nt][r];
            } else if (EPI == 1) {
#pragma unroll
                for (int r = 0; r < 4; ++r) {
                    float v = acc[mt][nt][r];
                    unsigned short h = f2bf(v);
                    ((unsigned short*)O0)[(size_t)(row0 + r) * N + col] = h;
                    ((unsigned short*)O1)[(size_t)(row0 + r) * N + col] =
                        f2bf(v - bf2f(h));
                }
            } else {  // EPI == 2: Vt[b][h][d][s]; rows are consecutive s
                const int b = row0 >> 11, s = row0 & 2047;
                const int hh = col >> 6, d = col & 63;
                unsigned short vs[4];
#pragma unroll
                for (int r = 0; r < 4; ++r) vs[r] = f2bf(acc[mt][nt][r]);
                *(ushort4*)((unsigned short*)O0 +
                            (((size_t)(b * HEADS + hh)) * HD + d) * SEQ + s) =
                    *(ushort4*)vs;
            }
        }
}

// ---------------------------------------------------------------------------
// MFMA flash attention. Block = (b, h, 64-row Q tile), 256 threads = 4 waves;
// wave w owns q-rows 16w..16w+15 (softmax state wave-private).
// QK^T: 3-pass split-bf16 (fp32-grade logits). PV: plain bf16.
// Q,K layouts: [B*S][DM] split bf16. V: pre-transposed Vt[b][h][d][s] bf16.
// P: C-layout -> LDS (bf16) -> A-layout, wave-private strip.
// LDS pitch 72 (144 B): rows 16B-aligned, frag reads uniform 2-way (free).
// ---------------------------------------------------------------------------
__global__ __launch_bounds__(256) void attn_mfma(
    const unsigned short* __restrict__ Qh, const unsigned short* __restrict__ Ql,
    const unsigned short* __restrict__ Kh, const unsigned short* __restrict__ Kl,
    const unsigned short* __restrict__ Vt, unsigned short* __restrict__ Oc)
{
    __shared__ unsigned short Qh_s[64][72], Ql_s[64][72];
    __shared__ unsigned short Kh_s[64][72], Kl_s[64][72];
    __shared__ unsigned short Vt_s[64][72], P_s[64][72];

    const int t = threadIdx.x;
    const int w = t >> 6, lane = t & 63, quad = lane >> 4, l15 = lane & 15;
    const int b = blockIdx.z, h = blockIdx.y, q0 = blockIdx.x * 64;

    const size_t qk_base = ((size_t)b * SEQ) * DM + h * HD;
    const size_t vt_base = ((size_t)(b * HEADS + h)) * HD * SEQ;

    const int srow = t >> 2, scol = (t & 3) << 4;  // 64 rows x 64 cols staging

    {   // stage Q tile (hi+lo), persistent
        const size_t g = qk_base + (size_t)(q0 + srow) * DM + scol;
        *(float4*)&Qh_s[srow][scol]     = *(const float4*)(Qh + g);
        *(float4*)&Qh_s[srow][scol + 8] = *(const float4*)(Qh + g + 8);
        *(float4*)&Ql_s[srow][scol]     = *(const float4*)(Ql + g);
        *(float4*)&Ql_s[srow][scol + 8] = *(const float4*)(Ql + g + 8);
    }
    __syncthreads();

    // Hoist Q A-frags: A[m = lane&15][k = quad*8 + j], k-steps of 32
    short8 aQh[2], aQl[2];
#pragma unroll
    for (int ks = 0; ks < 2; ++ks) {
        aQh[ks] = *(const short8*)&Qh_s[w * 16 + l15][ks * 32 + quad * 8];
        aQl[ks] = *(const short8*)&Ql_s[w * 16 + l15][ks * 32 + quad * 8];
    }

    f32x4 o_acc[4];
    float m_r[4], l_r[4];
#pragma unroll
    for (int nt = 0; nt < 4; ++nt)
#pragma unroll
        for (int r = 0; r < 4; ++r) o_acc[nt][r] = 0.f;
#pragma unroll
    for (int r = 0; r < 4; ++r) { m_r[r] = -INFINITY; l_r[r] = 0.f; }

    for (int k0 = 0; k0 < SEQ; k0 += 64) {
        __syncthreads();  // prior iter's K/V frag reads complete
        {   // stage K (hi+lo) and Vt tiles
            const size_t gk = qk_base + (size_t)(k0 + srow) * DM + scol;
            *(float4*)&Kh_s[srow][scol]     = *(const float4*)(Kh + gk);
            *(float4*)&Kh_s[srow][scol + 8] = *(const float4*)(Kh + gk + 8);
            *(float4*)&Kl_s[srow][scol]     = *(const float4*)(Kl + gk);
            *(float4*)&Kl_s[srow][scol + 8] = *(const float4*)(Kl + gk + 8);
            const size_t gv = vt_base + (size_t)srow * SEQ + k0 + scol;
            *(float4*)&Vt_s[srow][scol]     = *(const float4*)(Vt + gv);
            *(float4*)&Vt_s[srow][scol + 8] = *(const float4*)(Vt + gv + 8);
        }
        __syncthreads();

        // S = Q K^T (3-pass split)
        f32x4 s_acc[4];
#pragma unroll
        for (int nt = 0; nt < 4; ++nt)
#pragma unroll
            for (int r = 0; r < 4; ++r) s_acc[nt][r] = 0.f;
#pragma unroll
        for (int nt = 0; nt < 4; ++nt)
#pragma unroll
            for (int ks = 0; ks < 2; ++ks) {
                short8 bKh = *(const short8*)&Kh_s[nt * 16 + l15][ks * 32 + quad * 8];
                short8 bKl = *(const short8*)&Kl_s[nt * 16 + l15][ks * 32 + quad * 8];
                s_acc[nt] = __builtin_amdgcn_mfma_f32_16x16x32_bf16(
                    aQh[ks], bKh, s_acc[nt], 0, 0, 0);
                s_acc[nt] = __builtin_amdgcn_mfma_f32_16x16x32_bf16(
                    aQh[ks], bKl, s_acc[nt], 0, 0, 0);
                s_acc[nt] = __builtin_amdgcn_mfma_f32_16x16x32_bf16(
                    aQl[ks], bKh, s_acc[nt], 0, 0, 0);
            }

        // Online softmax (rows quad*4+r; row's 64 cols live in 16 lanes x 4 nt)
#pragma unroll
        for (int nt = 0; nt < 4; ++nt)
#pragma unroll
            for (int r = 0; r < 4; ++r) s_acc[nt][r] *= 0.125f;

        float alpha[4];
#pragma unroll
        for (int r = 0; r < 4; ++r) {
            float mx = fmaxf(fmaxf(s_acc[0][r], s_acc[1][r]),
                             fmaxf(s_acc[2][r], s_acc[3][r]));
            mx = fmaxf(mx, __shfl_xor(mx, 1));
            mx = fmaxf(mx, __shfl_xor(mx, 2));
            mx = fmaxf(mx, __shfl_xor(mx, 4));
            mx = fmaxf(mx, __shfl_xor(mx, 8));
            const float nm = fmaxf(m_r[r], mx);
            alpha[r] = __expf(m_r[r] - nm);
            m_r[r] = nm;
            float rs = 0.f;
#pragma unroll
            for (int nt = 0; nt < 4; ++nt) {
                float p = __expf(s_acc[nt][r] - nm);
                s_acc[nt][r] = p;
                rs += p;
            }
            rs += __shfl_xor(rs, 1);
            rs += __shfl_xor(rs, 2);
            rs += __shfl_xor(rs, 4);
            rs += __shfl_xor(rs, 8);
            l_r[r] = l_r[r] * alpha[r] + rs;
        }

        // P -> LDS (wave-private 16-row strip), rescale O
#pragma unroll
        for (int nt = 0; nt < 4; ++nt)
#pragma unroll
            for (int r = 0; r < 4; ++r)
                P_s[w * 16 + quad * 4 + r][nt * 16 + l15] = f2bf(s_acc[nt][r]);
#pragma unroll
        for (int nt = 0; nt < 4; ++nt)
#pragma unroll
            for (int r = 0; r < 4; ++r) o_acc[nt][r] *= alpha[r];

        // O += P V   (A = P from LDS, B = Vt rows)
#pragma unroll
        for (int ks = 0; ks < 2; ++ks) {
            short8 aP = *(const short8*)&P_s[w * 16 + l15][ks * 32 + quad * 8];
#pragma unroll
            for (int nt = 0; nt < 4; ++nt) {
                short8 bV = *(const short8*)&Vt_s[nt * 16 + l15][ks * 32 + quad * 8];
                o_acc[nt] = __builtin_amdgcn_mfma_f32_16x16x32_bf16(
                    aP, bV, o_acc[nt], 0, 0, 0);
            }
        }
    }

    // Epilogue: concat[b, q, h*64+d] bf16
#pragma unroll
    for (int nt = 0; nt < 4; ++nt)
#pragma unroll
        for (int r = 0; r < 4; ++r) {
            const int row = q0 + w * 16 + quad * 4 + r;
            const int col = h * HD + nt * 16 + l15;
            Oc[((size_t)b * SEQ + row) * DM + col] = f2bf(o_acc[nt][r] / l_r[r]);
        }
}

// ---------------------------------------------------------------------------
extern "C" void kernel_launch(void* const* d_in, const int* in_sizes, int n_in,
                              void* d_out, int out_size, void* d_ws, size_t ws_size,
                              hipStream_t stream) {
    const float* x  = (const float*)d_in[0];
    const float* Wq = (const float*)d_in[1];
    const float* Wk = (const float*)d_in[2];
    const float* Wv = (const float*)d_in[3];
    const float* Wo = (const float*)d_in[4];
    float* out = (float*)d_out;

    char* ws = (char*)d_ws;
    const size_t SZ_TOK = (size_t)M_TOK * DM * 2;  // 16 MB (bf16 token matrix)
    const size_t SZ_W   = (size_t)DM * DM * 2;     // 2 MB

    unsigned short* xh     = (unsigned short*)(ws);
    unsigned short* xl     = (unsigned short*)(ws + SZ_TOK);
    unsigned short* Wqt_h  = (unsigned short*)(ws + 2 * SZ_TOK);
    unsigned short* Wqt_l  = (unsigned short*)(ws + 2 * SZ_TOK + SZ_W);
    unsigned short* Wkt_h  = (unsigned short*)(ws + 2 * SZ_TOK + 2 * SZ_W);
    unsigned short* Wkt_l  = (unsigned short*)(ws + 2 * SZ_TOK + 3 * SZ_W);
    unsigned short* Wvt    = (unsigned short*)(ws + 2 * SZ_TOK + 4 * SZ_W);
    unsigned short* Wot    = (unsigned short*)(ws + 2 * SZ_TOK + 5 * SZ_W);
    unsigned short* Qh_    = (unsigned short*)(ws + 2 * SZ_TOK + 6 * SZ_W);
    unsigned short* Ql_    = (unsigned short*)(ws + 3 * SZ_TOK + 6 * SZ_W);
    unsigned short* Kh_    = (unsigned short*)(ws + 4 * SZ_TOK + 6 * SZ_W);
    unsigned short* Kl_    = (unsigned short*)(ws + 5 * SZ_TOK + 6 * SZ_W);
    unsigned short* Vt_    = (unsigned short*)(ws + 6 * SZ_TOK + 6 * SZ_W);
    unsigned short* concat = xh;  // x dead after V projection; reuse (16 MB)

    dim3 blk(256);

    hipLaunchKernelGGL(split_cast, dim3(M_TOK * DM / (256 * 8)), blk, 0, stream,
                       x, xh, xl);
    dim3 wgrid(DM / 64, DM / 64);
    hipLaunchKernelGGL((wtrans<1>), wgrid, blk, 0, stream, Wq, Wqt_h, Wqt_l);
    hipLaunchKernelGGL((wtrans<1>), wgrid, blk, 0, stream, Wk, Wkt_h, Wkt_l);
    hipLaunchKernelGGL((wtrans<0>), wgrid, blk, 0, stream, Wv, Wvt, nullptr);
    hipLaunchKernelGGL((wtrans<0>), wgrid, blk, 0, stream, Wo, Wot, nullptr);

    dim3 ggrid(DM / 128, M_TOK / 128);  // 8 x 64
    hipLaunchKernelGGL((gemm_bt<3, 1>), ggrid, blk, 0, stream,
                       xh, xl, Wqt_h, Wqt_l, Qh_, Ql_, M_TOK, DM, DM);
    hipLaunchKernelGGL((gemm_bt<3, 1>), ggrid, blk, 0, stream,
                       xh, xl, Wkt_h, Wkt_l, Kh_, Kl_, M_TOK, DM, DM);
    hipLaunchKernelGGL((gemm_bt<1, 2>), ggrid, blk, 0, stream,
                       xh, nullptr, Wvt, nullptr, Vt_, nullptr, M_TOK, DM, DM);

    dim3 agrid(SEQ / 64, HEADS, BATCH);  // 32 x 16 x 4
    hipLaunchKernelGGL(attn_mfma, agrid, blk, 0, stream,
                       Qh_, Ql_, Kh_, Kl_, Vt_, concat);

    hipLaunchKernelGGL((gemm_bt<1, 0>), ggrid, blk, 0, stream,
                       concat, nullptr, Wot, nullptr, out, nullptr, M_TOK, DM, DM);
}

// Round 4
// 550.047 us; speedup vs baseline: 3.7792x; 1.1453x over previous
//
#include <hip/hip_runtime.h>
#include <hip/hip_fp16.h>

#define BATCH   4
#define SEQ     2048
#define DM      1024
#define HEADS   16
#define HD      64
#define M_TOK   (BATCH * SEQ)   // 8192

// 0.125 (1/sqrt(64)) * log2(e): folded into Wq so logits come out in log2 units.
#define QSCALE  0.1803368801111204f

typedef __attribute__((ext_vector_type(8))) _Float16 half8;
typedef __attribute__((ext_vector_type(4))) float    f32x4;

__device__ __forceinline__ unsigned short f2h(float x) {
    return __half_as_ushort(__float2half(x));
}
__device__ __forceinline__ float h2f(unsigned short u) {
    return __half2float(__ushort_as_half(u));
}
// v_exp_f32 IS exp2 on gfx9xx.
__device__ __forceinline__ float fast_exp2(float x) {
    float r; asm volatile("v_exp_f32 %0, %1" : "=v"(r) : "v"(x)); return r;
}
// async global->LDS DMA, 16B per lane; LDS dest = uniform base + lane*16.
__device__ __forceinline__ void dma16(const void* g, void* l) {
    __builtin_amdgcn_global_load_lds(
        (const __attribute__((address_space(1))) void*)g,
        (__attribute__((address_space(3))) void*)l, 16, 0, 0);
}

// ---------------------------------------------------------------------------
// x -> hi/lo f16 split (elementwise)
// ---------------------------------------------------------------------------
__global__ __launch_bounds__(256) void split_cast(
    const float* __restrict__ x, unsigned short* __restrict__ hi,
    unsigned short* __restrict__ lo)
{
    const int i = (blockIdx.x * 256 + threadIdx.x) * 8;
    float4 a = *(const float4*)(x + i);
    float4 b = *(const float4*)(x + i + 4);
    float v[8] = {a.x, a.y, a.z, a.w, b.x, b.y, b.z, b.w};
    unsigned short hb[8], lb[8];
#pragma unroll
    for (int j = 0; j < 8; ++j) {
        hb[j] = f2h(v[j]);
        lb[j] = f2h(v[j] - h2f(hb[j]));
    }
    *(float4*)(hi + i) = *(float4*)hb;
    *(float4*)(lo + i) = *(float4*)lb;
}

// ---------------------------------------------------------------------------
// Weight transpose (+scale, +optional split): W[K][N] f32 -> Wt[N][K] f16
// ---------------------------------------------------------------------------
template<int SPLIT>
__global__ __launch_bounds__(256) void wtrans(
    const float* __restrict__ W, unsigned short* __restrict__ Th_out,
    unsigned short* __restrict__ Tl_out, float scale)
{
    __shared__ unsigned short Th[64][72];
    __shared__ unsigned short Tl[SPLIT ? 64 : 1][72];
    const int t  = threadIdx.x;
    const int n0 = blockIdx.x * 64, k0 = blockIdx.y * 64;
    const int kr = t >> 2, cg = (t & 3) << 4;
#pragma unroll
    for (int jj = 0; jj < 16; jj += 4) {
        float4 wv = *(const float4*)(W + (size_t)(k0 + kr) * DM + n0 + cg + jj);
        float vv[4] = {wv.x, wv.y, wv.z, wv.w};
#pragma unroll
        for (int j = 0; j < 4; ++j) {
            float v = vv[j] * scale;
            unsigned short h = f2h(v);
            Th[cg + jj + j][kr] = h;
            if (SPLIT) Tl[cg + jj + j][kr] = f2h(v - h2f(h));
        }
    }
    __syncthreads();
    const int nr = t >> 2, kg = (t & 3) << 4;
    size_t go = (size_t)(n0 + nr) * DM + k0 + kg;
    *(float4*)(Th_out + go)     = *(float4*)&Th[nr][kg];
    *(float4*)(Th_out + go + 8) = *(float4*)&Th[nr][kg + 8];
    if (SPLIT) {
        *(float4*)(Tl_out + go)     = *(float4*)&Tl[nr][kg];
        *(float4*)(Tl_out + go + 8) = *(float4*)&Tl[nr][kg + 8];
    }
}

// ---------------------------------------------------------------------------
// f16 MFMA GEMM, m97 structure: C = A[M,K] @ Bt[N,K]^T, 128x128 tile, BK=32,
// global_load_lds 16B staging into UNPADDED [128][32] tiles.
// PASSES: 1 = plain; 3 = hi/lo split (A*B + A*Bl + Al*B) fp32-grade.
// EPI: 0 = f32 out; 1 = split-f16 out (O0 hi, O1 lo); 2 = f16 out;
//      3 = per-head-transposed f16 V (O0 = Vt[b][h][d][s]).
// ---------------------------------------------------------------------------
template<int PASSES, int EPI>
__global__ __launch_bounds__(256, 2) void gemm_f16(
    const unsigned short* __restrict__ Ah, const unsigned short* __restrict__ Al,
    const unsigned short* __restrict__ Bh, const unsigned short* __restrict__ Bl,
    void* __restrict__ O0, void* __restrict__ O1, int M, int N, int K)
{
    __shared__ unsigned short As_h[128 * 32];
    __shared__ unsigned short Bs_h[128 * 32];
    __shared__ unsigned short As_l[PASSES == 3 ? 128 * 32 : 16];
    __shared__ unsigned short Bs_l[PASSES == 3 ? 128 * 32 : 16];

    const int t = threadIdx.x;
    const int w = t >> 6, lane = t & 63, quad = lane >> 4, l15 = lane & 15;
    const int wm = w >> 1, wn = w & 1;
    const int m0 = blockIdx.y * 128, n0 = blockIdx.x * 128;

    // DMA mapping: wave w stages rows [w*32, w*32+32); instr covers 16 rows.
    const int drow = w * 32 + (lane >> 2);
    const int dcol = (lane & 3) * 8;

    f32x4 acc[4][4];
#pragma unroll
    for (int mt = 0; mt < 4; ++mt)
#pragma unroll
        for (int nt = 0; nt < 4; ++nt)
#pragma unroll
            for (int r = 0; r < 4; ++r) acc[mt][nt][r] = 0.f;

    for (int k0 = 0; k0 < K; k0 += 32) {
        __syncthreads();  // prior-iter frag reads done
#pragma unroll
        for (int inst = 0; inst < 2; ++inst) {
            const size_t ga = (size_t)(m0 + drow + inst * 16) * K + k0 + dcol;
            const size_t gb = (size_t)(n0 + drow + inst * 16) * K + k0 + dcol;
            const int lo = (w * 32 + inst * 16) * 32;
            dma16(Ah + ga, &As_h[lo]);
            dma16(Bh + gb, &Bs_h[lo]);
            if (PASSES == 3) {
                dma16(Al + ga, &As_l[lo]);
                dma16(Bl + gb, &Bs_l[lo]);
            }
        }
        __syncthreads();  // drains vmcnt(0): DMA complete

        half8 aH[4], bH[4], aL[4], bL[4];
#pragma unroll
        for (int mt = 0; mt < 4; ++mt) {
            const int row = wm * 64 + mt * 16 + l15;
            aH[mt] = *(const half8*)&As_h[row * 32 + quad * 8];
            if (PASSES == 3) aL[mt] = *(const half8*)&As_l[row * 32 + quad * 8];
        }
#pragma unroll
        for (int nt = 0; nt < 4; ++nt) {
            const int row = wn * 64 + nt * 16 + l15;
            bH[nt] = *(const half8*)&Bs_h[row * 32 + quad * 8];
            if (PASSES == 3) bL[nt] = *(const half8*)&Bs_l[row * 32 + quad * 8];
        }
#pragma unroll
        for (int mt = 0; mt < 4; ++mt)
#pragma unroll
            for (int nt = 0; nt < 4; ++nt) {
                acc[mt][nt] = __builtin_amdgcn_mfma_f32_16x16x32_f16(
                    aH[mt], bH[nt], acc[mt][nt], 0, 0, 0);
                if (PASSES == 3) {
                    acc[mt][nt] = __builtin_amdgcn_mfma_f32_16x16x32_f16(
                        aH[mt], bL[nt], acc[mt][nt], 0, 0, 0);
                    acc[mt][nt] = __builtin_amdgcn_mfma_f32_16x16x32_f16(
                        aL[mt], bH[nt], acc[mt][nt], 0, 0, 0);
                }
            }
    }

    // Epilogue. C/D layout: col = lane&15, row = quad*4 + reg.
#pragma unroll
    for (int mt = 0; mt < 4; ++mt)
#pragma unroll
        for (int nt = 0; nt < 4; ++nt) {
            const int row0 = m0 + wm * 64 + mt * 16 + quad * 4;
            const int col  = n0 + wn * 64 + nt * 16 + l15;
            if (EPI == 0) {
#pragma unroll
                for (int r = 0; r < 4; ++r)
                    ((float*)O0)[(size_t)(row0 + r) * N + col] = acc[mt][nt][r];
            } else if (EPI == 1) {
#pragma unroll
                for (int r = 0; r < 4; ++r) {
                    float v = acc[mt][nt][r];
                    unsigned short h = f2h(v);
                    ((unsigned short*)O0)[(size_t)(row0 + r) * N + col] = h;
                    ((unsigned short*)O1)[(size_t)(row0 + r) * N + col] =
                        f2h(v - h2f(h));
                }
            } else if (EPI == 2) {
#pragma unroll
                for (int r = 0; r < 4; ++r)
                    ((unsigned short*)O0)[(size_t)(row0 + r) * N + col] =
                        f2h(acc[mt][nt][r]);
            } else {  // EPI == 3: Vt[b][h][d][s]; regs are consecutive s
                const int b = row0 >> 11, s = row0 & 2047;
                const int hh = col >> 6, d = col & 63;
                unsigned short vs[4];
#pragma unroll
                for (int r = 0; r < 4; ++r) vs[r] = f2h(acc[mt][nt][r]);
                *(ushort4*)((unsigned short*)O0 +
                            (((size_t)(b * HEADS + hh)) * HD + d) * SEQ + s) =
                    *(ushort4*)vs;
            }
        }
}

// ---------------------------------------------------------------------------
// f16 MFMA flash attention. Block = (b, h, 128-row Q tile), 4 waves, wave owns
// 32 q-rows (2 strips of 16) -> K/V B-frags reused x2.
// QK^T: 3-pass split (Qh*Kh + Qh*Kl + Ql*Kh) -> logit error ~1e-4 log2 units
// (the 389-absmax R3 failure was single-f16 K: 0.36 log2 -> argmax flips).
// Logits in log2 units (QSCALE folded into Wq); softmax = raw v_exp_f32.
// Row-sum l via ones-column MFMA. LDS layout: QP[128*128] holds Qh|Ql during
// init; in-loop it holds P (pitch 72, [0,9216)) and Kl tile ([9216,13824)).
// Total 50 KB -> 3 blocks/CU.
// ---------------------------------------------------------------------------
__global__ __launch_bounds__(256, 3) void attn_f16(
    const unsigned short* __restrict__ Qh, const unsigned short* __restrict__ Ql,
    const unsigned short* __restrict__ Kh, const unsigned short* __restrict__ Kl,
    const unsigned short* __restrict__ Vt, unsigned short* __restrict__ Oc)
{
    __shared__ unsigned short QP[128 * 128];
    __shared__ unsigned short Ks[64 * 72];
    __shared__ unsigned short Vs[64 * 72];
    unsigned short* Qh_s = QP;
    unsigned short* Ql_s = QP + 128 * 64;
    unsigned short* P_s  = QP;               // [128][72], wave-private strips
    unsigned short* Ksl  = QP + 128 * 72;    // [64][72] Kl tile (9216..13824)

    const int t = threadIdx.x;
    const int w = t >> 6, lane = t & 63, quad = lane >> 4, l15 = lane & 15;
    const int b = blockIdx.z, h = blockIdx.y, q0 = blockIdx.x * 128;

    const size_t qk_base = ((size_t)b * SEQ) * DM + h * HD;
    const size_t vt_base = ((size_t)(b * HEADS + h)) * HD * SEQ;

    {   // stage Q tile: 128 rows x 64 f16, hi+lo
        const int srow = t >> 1, scol = (t & 1) << 5;
        const size_t g = qk_base + (size_t)(q0 + srow) * DM + scol;
#pragma unroll
        for (int c = 0; c < 32; c += 8) {
            *(float4*)&Qh_s[srow * 64 + scol + c] = *(const float4*)(Qh + g + c);
            *(float4*)&Ql_s[srow * 64 + scol + c] = *(const float4*)(Ql + g + c);
        }
    }
    __syncthreads();

    // Hoist Q A-frags (2 strips x 2 k-steps, hi+lo). Q LDS dead after this.
    half8 aQh[2][2], aQl[2][2];
#pragma unroll
    for (int st = 0; st < 2; ++st)
#pragma unroll
        for (int ks = 0; ks < 2; ++ks) {
            const int row = w * 32 + st * 16 + l15;
            aQh[st][ks] = *(const half8*)&Qh_s[row * 64 + ks * 32 + quad * 8];
            aQl[st][ks] = *(const half8*)&Ql_s[row * 64 + ks * 32 + quad * 8];
        }

    half8 ones;
#pragma unroll
    for (int j = 0; j < 8; ++j) ones[j] = (_Float16)1.0f;

    // o_acc[st][0..3] = O tiles; o_acc[st][4] = running row-sum l (ones trick)
    f32x4 o_acc[2][5];
    float m_r[2][4];
#pragma unroll
    for (int st = 0; st < 2; ++st) {
#pragma unroll
        for (int nt = 0; nt < 5; ++nt)
#pragma unroll
            for (int r = 0; r < 4; ++r) o_acc[st][nt][r] = 0.f;
#pragma unroll
        for (int r = 0; r < 4; ++r) m_r[st][r] = -3.0e38f;
    }

    const int srow = t >> 2, scol = (t & 3) << 4;  // K/V staging: 64x64 f16

    for (int k0 = 0; k0 < SEQ; k0 += 64) {
        __syncthreads();  // prior-iter frag reads (and Q hoist at iter 0) done
        {
            const size_t gk = qk_base + (size_t)(k0 + srow) * DM + scol;
            *(float4*)&Ks[srow * 72 + scol]      = *(const float4*)(Kh + gk);
            *(float4*)&Ks[srow * 72 + scol + 8]  = *(const float4*)(Kh + gk + 8);
            *(float4*)&Ksl[srow * 72 + scol]     = *(const float4*)(Kl + gk);
            *(float4*)&Ksl[srow * 72 + scol + 8] = *(const float4*)(Kl + gk + 8);
            const size_t gv = vt_base + (size_t)srow * SEQ + k0 + scol;
            *(float4*)&Vs[srow * 72 + scol]      = *(const float4*)(Vt + gv);
            *(float4*)&Vs[srow * 72 + scol + 8]  = *(const float4*)(Vt + gv + 8);
        }
        __syncthreads();

        // S = Q K^T, 3-pass split; B-frags reused across both strips
        f32x4 s_acc[2][4];
#pragma unroll
        for (int st = 0; st < 2; ++st)
#pragma unroll
            for (int nt = 0; nt < 4; ++nt)
#pragma unroll
                for (int r = 0; r < 4; ++r) s_acc[st][nt][r] = 0.f;
#pragma unroll
        for (int nt = 0; nt < 4; ++nt)
#pragma unroll
            for (int ks = 0; ks < 2; ++ks) {
                const int bro = (nt * 16 + l15) * 72 + ks * 32 + quad * 8;
                half8 bKh = *(const half8*)&Ks[bro];
                half8 bKl = *(const half8*)&Ksl[bro];
#pragma unroll
                for (int st = 0; st < 2; ++st) {
                    s_acc[st][nt] = __builtin_amdgcn_mfma_f32_16x16x32_f16(
                        aQh[st][ks], bKh, s_acc[st][nt], 0, 0, 0);
                    s_acc[st][nt] = __builtin_amdgcn_mfma_f32_16x16x32_f16(
                        aQh[st][ks], bKl, s_acc[st][nt], 0, 0, 0);
                    s_acc[st][nt] = __builtin_amdgcn_mfma_f32_16x16x32_f16(
                        aQl[st][ks], bKh, s_acc[st][nt], 0, 0, 0);
                }
            }

        // Online softmax (logits already in log2 units). l handled by MFMA.
#pragma unroll
        for (int st = 0; st < 2; ++st) {
#pragma unroll
            for (int r = 0; r < 4; ++r) {
                float mx = fmaxf(fmaxf(s_acc[st][0][r], s_acc[st][1][r]),
                                 fmaxf(s_acc[st][2][r], s_acc[st][3][r]));
                mx = fmaxf(mx, __shfl_xor(mx, 1));
                mx = fmaxf(mx, __shfl_xor(mx, 2));
                mx = fmaxf(mx, __shfl_xor(mx, 4));
                mx = fmaxf(mx, __shfl_xor(mx, 8));
                const float nm = fmaxf(m_r[st][r], mx);
                const float al = fast_exp2(m_r[st][r] - nm);
                m_r[st][r] = nm;
                const int prow = (w * 32 + st * 16 + quad * 4 + r) * 72;
#pragma unroll
                for (int nt = 0; nt < 4; ++nt) {
                    float p = fast_exp2(s_acc[st][nt][r] - nm);
                    P_s[prow + nt * 16 + l15] = f2h(p);
                }
#pragma unroll
                for (int nt = 0; nt < 5; ++nt) o_acc[st][nt][r] *= al;
            }
        }

        // O += P V ; l += P * ones  (P is wave-private: no barrier needed)
#pragma unroll
        for (int ks = 0; ks < 2; ++ks) {
            half8 aP[2];
#pragma unroll
            for (int st = 0; st < 2; ++st)
                aP[st] = *(const half8*)&P_s[(w * 32 + st * 16 + l15) * 72 +
                                             ks * 32 + quad * 8];
#pragma unroll
            for (int nt = 0; nt < 4; ++nt) {
                half8 bV = *(const half8*)&Vs[(nt * 16 + l15) * 72 + ks * 32 + quad * 8];
#pragma unroll
                for (int st = 0; st < 2; ++st)
                    o_acc[st][nt] = __builtin_amdgcn_mfma_f32_16x16x32_f16(
                        aP[st], bV, o_acc[st][nt], 0, 0, 0);
            }
#pragma unroll
            for (int st = 0; st < 2; ++st)
                o_acc[st][4] = __builtin_amdgcn_mfma_f32_16x16x32_f16(
                    aP[st], ones, o_acc[st][4], 0, 0, 0);
        }
    }

    // Epilogue: concat[b, q, h*64+d] f16, rows normalized by l from ones-MFMA
#pragma unroll
    for (int st = 0; st < 2; ++st)
#pragma unroll
        for (int r = 0; r < 4; ++r) {
            const float inv = 1.0f / o_acc[st][4][r];
            const int row = q0 + w * 32 + st * 16 + quad * 4 + r;
#pragma unroll
            for (int nt = 0; nt < 4; ++nt) {
                const int col = h * HD + nt * 16 + l15;
                Oc[((size_t)b * SEQ + row) * DM + col] =
                    f2h(o_acc[st][nt][r] * inv);
            }
        }
}

// ---------------------------------------------------------------------------
extern "C" void kernel_launch(void* const* d_in, const int* in_sizes, int n_in,
                              void* d_out, int out_size, void* d_ws, size_t ws_size,
                              hipStream_t stream) {
    const float* x  = (const float*)d_in[0];
    const float* Wq = (const float*)d_in[1];
    const float* Wk = (const float*)d_in[2];
    const float* Wv = (const float*)d_in[3];
    const float* Wo = (const float*)d_in[4];
    float* out = (float*)d_out;

    char* ws = (char*)d_ws;
    const size_t SZ_TOK = (size_t)M_TOK * DM * 2;  // 16 MB f16 token matrix
    const size_t SZ_W   = (size_t)DM * DM * 2;     // 2 MB

    unsigned short* xh    = (unsigned short*)(ws);
    unsigned short* xl    = (unsigned short*)(ws + SZ_TOK);
    unsigned short* Wqt_h = (unsigned short*)(ws + 2 * SZ_TOK);
    unsigned short* Wqt_l = (unsigned short*)(ws + 2 * SZ_TOK + SZ_W);
    unsigned short* Wkt_h = (unsigned short*)(ws + 2 * SZ_TOK + 2 * SZ_W);
    unsigned short* Wkt_l = (unsigned short*)(ws + 2 * SZ_TOK + 3 * SZ_W);
    unsigned short* Wvt   = (unsigned short*)(ws + 2 * SZ_TOK + 4 * SZ_W);
    unsigned short* Wot   = (unsigned short*)(ws + 2 * SZ_TOK + 5 * SZ_W);
    unsigned short* Qh_   = (unsigned short*)(ws + 2 * SZ_TOK + 6 * SZ_W);
    unsigned short* Ql_   = (unsigned short*)(ws + 3 * SZ_TOK + 6 * SZ_W);
    unsigned short* Kh_   = (unsigned short*)(ws + 4 * SZ_TOK + 6 * SZ_W);
    unsigned short* Kl_   = (unsigned short*)(ws + 5 * SZ_TOK + 6 * SZ_W);
    unsigned short* Vt_   = (unsigned short*)(ws + 6 * SZ_TOK + 6 * SZ_W);
    unsigned short* concat = xh;  // x dead after V projection

    dim3 blk(256);

    hipLaunchKernelGGL(split_cast, dim3(M_TOK * DM / (256 * 8)), blk, 0, stream,
                       x, xh, xl);
    dim3 wgrid(DM / 64, DM / 64);
    hipLaunchKernelGGL((wtrans<1>), wgrid, blk, 0, stream, Wq, Wqt_h, Wqt_l, QSCALE);
    hipLaunchKernelGGL((wtrans<1>), wgrid, blk, 0, stream, Wk, Wkt_h, Wkt_l, 1.0f);
    hipLaunchKernelGGL((wtrans<0>), wgrid, blk, 0, stream, Wv, Wvt, nullptr, 1.0f);
    hipLaunchKernelGGL((wtrans<0>), wgrid, blk, 0, stream, Wo, Wot, nullptr, 1.0f);

    dim3 ggrid(DM / 128, M_TOK / 128);  // 8 x 64
    hipLaunchKernelGGL((gemm_f16<3, 1>), ggrid, blk, 0, stream,
                       xh, xl, Wqt_h, Wqt_l, Qh_, Ql_, M_TOK, DM, DM);
    hipLaunchKernelGGL((gemm_f16<3, 1>), ggrid, blk, 0, stream,
                       xh, xl, Wkt_h, Wkt_l, Kh_, Kl_, M_TOK, DM, DM);
    hipLaunchKernelGGL((gemm_f16<1, 3>), ggrid, blk, 0, stream,
                       xh, nullptr, Wvt, nullptr, Vt_, nullptr, M_TOK, DM, DM);

    dim3 agrid(SEQ / 128, HEADS, BATCH);  // 16 x 16 x 4 = 1024 blocks
    hipLaunchKernelGGL(attn_f16, agrid, blk, 0, stream,
                       Qh_, Ql_, Kh_, Kl_, Vt_, concat);

    hipLaunchKernelGGL((gemm_f16<1, 0>), ggrid, blk, 0, stream,
                       concat, nullptr, Wot, nullptr, out, nullptr, M_TOK, DM, DM);
}

// Round 6
// 485.853 us; speedup vs baseline: 4.2785x; 1.1321x over previous
//
#include <hip/hip_runtime.h>
#include <hip/hip_fp16.h>

#define BATCH   4
#define SEQ     2048
#define DM      1024
#define HEADS   16
#define HD      64
#define M_TOK   (BATCH * SEQ)   // 8192
#define QK_LD   2048            // merged Q|K projection leading dim

// 0.125 (1/sqrt(64)) * log2(e): folded into Wq so logits come out in log2 units.
#define QSCALE  0.1803368801111204f

typedef __attribute__((ext_vector_type(8)))  _Float16 half8;
typedef __attribute__((ext_vector_type(4)))  float    f32x4;
typedef __attribute__((ext_vector_type(16))) float    f32x16;

__device__ __forceinline__ unsigned short f2h(float x) {
    return __half_as_ushort(__float2half(x));
}
__device__ __forceinline__ float h2f(unsigned short u) {
    return __half2float(__ushort_as_half(u));
}
// v_exp_f32 IS exp2 on gfx9xx.
__device__ __forceinline__ float fast_exp2(float x) {
    float r; asm volatile("v_exp_f32 %0, %1" : "=v"(r) : "v"(x)); return r;
}
// pack two f32 -> f16x2 in one VGPR (v_cvt_pkrtz_f16_f32), a in [15:0].
// NB: builtin returns __fp16 ext_vector(2) -- receive in that exact type.
__device__ __forceinline__ unsigned int pk2(float a, float b) {
    __fp16 __attribute__((ext_vector_type(2))) h =
        __builtin_amdgcn_cvt_pkrtz(a, b);
    return __builtin_bit_cast(unsigned int, h);
}
// async global->LDS DMA, 16B per lane; LDS dest = uniform base + lane*16.
__device__ __forceinline__ void dma16(const void* g, void* l) {
    __builtin_amdgcn_global_load_lds(
        (const __attribute__((address_space(1))) void*)g,
        (__attribute__((address_space(3))) void*)l, 16, 0, 0);
}

// ---------------------------------------------------------------------------
// x -> hi/lo f16 split (elementwise)
// ---------------------------------------------------------------------------
__global__ __launch_bounds__(256) void split_cast(
    const float* __restrict__ x, unsigned short* __restrict__ hi,
    unsigned short* __restrict__ lo)
{
    const int i = (blockIdx.x * 256 + threadIdx.x) * 8;
    float4 a = *(const float4*)(x + i);
    float4 b = *(const float4*)(x + i + 4);
    float v[8] = {a.x, a.y, a.z, a.w, b.x, b.y, b.z, b.w};
    unsigned short hb[8], lb[8];
#pragma unroll
    for (int j = 0; j < 8; ++j) {
        hb[j] = f2h(v[j]);
        lb[j] = f2h(v[j] - h2f(hb[j]));
    }
    *(float4*)(hi + i) = *(float4*)hb;
    *(float4*)(lo + i) = *(float4*)lb;
}

// ---------------------------------------------------------------------------
// Weight transpose (+scale, +optional split): W[K][N] f32 -> Wt[N][K] f16
// ---------------------------------------------------------------------------
template<int SPLIT>
__global__ __launch_bounds__(256) void wtrans(
    const float* __restrict__ W, unsigned short* __restrict__ Th_out,
    unsigned short* __restrict__ Tl_out, float scale)
{
    __shared__ unsigned short Th[64][72];
    __shared__ unsigned short Tl[SPLIT ? 64 : 1][72];
    const int t  = threadIdx.x;
    const int n0 = blockIdx.x * 64, k0 = blockIdx.y * 64;
    const int kr = t >> 2, cg = (t & 3) << 4;
#pragma unroll
    for (int jj = 0; jj < 16; jj += 4) {
        float4 wv = *(const float4*)(W + (size_t)(k0 + kr) * DM + n0 + cg + jj);
        float vv[4] = {wv.x, wv.y, wv.z, wv.w};
#pragma unroll
        for (int j = 0; j < 4; ++j) {
            float v = vv[j] * scale;
            unsigned short h = f2h(v);
            Th[cg + jj + j][kr] = h;
            if (SPLIT) Tl[cg + jj + j][kr] = f2h(v - h2f(h));
        }
    }
    __syncthreads();
    const int nr = t >> 2, kg = (t & 3) << 4;
    size_t go = (size_t)(n0 + nr) * DM + k0 + kg;
    *(float4*)(Th_out + go)     = *(float4*)&Th[nr][kg];
    *(float4*)(Th_out + go + 8) = *(float4*)&Th[nr][kg + 8];
    if (SPLIT) {
        *(float4*)(Tl_out + go)     = *(float4*)&Tl[nr][kg];
        *(float4*)(Tl_out + go + 8) = *(float4*)&Tl[nr][kg + 8];
    }
}

// ---------------------------------------------------------------------------
// f16 MFMA GEMM, m97 structure: C = A[M,K] @ Bt[N,K]^T, 128x128 tile, BK=32,
// global_load_lds 16B staging into UNPADDED [128][32] tiles.
// PASSES: 1 = plain; 3 = hi/lo split (A*B + A*Bl + Al*B) fp32-grade.
// EPI: 0 = f32 out; 1 = split-f16 out (O0 hi, O1 lo); 2 = f16 out;
//      3 = per-head-transposed f16 V (O0 = Vt[b][h][d][s]).
// ---------------------------------------------------------------------------
template<int PASSES, int EPI>
__global__ __launch_bounds__(256, 2) void gemm_f16(
    const unsigned short* __restrict__ Ah, const unsigned short* __restrict__ Al,
    const unsigned short* __restrict__ Bh, const unsigned short* __restrict__ Bl,
    void* __restrict__ O0, void* __restrict__ O1, int M, int N, int K)
{
    __shared__ unsigned short As_h[128 * 32];
    __shared__ unsigned short Bs_h[128 * 32];
    __shared__ unsigned short As_l[PASSES == 3 ? 128 * 32 : 16];
    __shared__ unsigned short Bs_l[PASSES == 3 ? 128 * 32 : 16];

    const int t = threadIdx.x;
    const int w = t >> 6, lane = t & 63, quad = lane >> 4, l15 = lane & 15;
    const int wm = w >> 1, wn = w & 1;
    const int m0 = blockIdx.y * 128, n0 = blockIdx.x * 128;

    const int drow = w * 32 + (lane >> 2);
    const int dcol = (lane & 3) * 8;

    f32x4 acc[4][4];
#pragma unroll
    for (int mt = 0; mt < 4; ++mt)
#pragma unroll
        for (int nt = 0; nt < 4; ++nt)
#pragma unroll
            for (int r = 0; r < 4; ++r) acc[mt][nt][r] = 0.f;

    for (int k0 = 0; k0 < K; k0 += 32) {
        __syncthreads();
#pragma unroll
        for (int inst = 0; inst < 2; ++inst) {
            const size_t ga = (size_t)(m0 + drow + inst * 16) * K + k0 + dcol;
            const size_t gb = (size_t)(n0 + drow + inst * 16) * K + k0 + dcol;
            const int lo = (w * 32 + inst * 16) * 32;
            dma16(Ah + ga, &As_h[lo]);
            dma16(Bh + gb, &Bs_h[lo]);
            if (PASSES == 3) {
                dma16(Al + ga, &As_l[lo]);
                dma16(Bl + gb, &Bs_l[lo]);
            }
        }
        __syncthreads();

        half8 aH[4], bH[4], aL[4], bL[4];
#pragma unroll
        for (int mt = 0; mt < 4; ++mt) {
            const int row = wm * 64 + mt * 16 + l15;
            aH[mt] = *(const half8*)&As_h[row * 32 + quad * 8];
            if (PASSES == 3) aL[mt] = *(const half8*)&As_l[row * 32 + quad * 8];
        }
#pragma unroll
        for (int nt = 0; nt < 4; ++nt) {
            const int row = wn * 64 + nt * 16 + l15;
            bH[nt] = *(const half8*)&Bs_h[row * 32 + quad * 8];
            if (PASSES == 3) bL[nt] = *(const half8*)&Bs_l[row * 32 + quad * 8];
        }
#pragma unroll
        for (int mt = 0; mt < 4; ++mt)
#pragma unroll
            for (int nt = 0; nt < 4; ++nt) {
                acc[mt][nt] = __builtin_amdgcn_mfma_f32_16x16x32_f16(
                    aH[mt], bH[nt], acc[mt][nt], 0, 0, 0);
                if (PASSES == 3) {
                    acc[mt][nt] = __builtin_amdgcn_mfma_f32_16x16x32_f16(
                        aH[mt], bL[nt], acc[mt][nt], 0, 0, 0);
                    acc[mt][nt] = __builtin_amdgcn_mfma_f32_16x16x32_f16(
                        aL[mt], bH[nt], acc[mt][nt], 0, 0, 0);
                }
            }
    }

    // Epilogue. C/D layout: col = lane&15, row = quad*4 + reg.
#pragma unroll
    for (int mt = 0; mt < 4; ++mt)
#pragma unroll
        for (int nt = 0; nt < 4; ++nt) {
            const int row0 = m0 + wm * 64 + mt * 16 + quad * 4;
            const int col  = n0 + wn * 64 + nt * 16 + l15;
            if (EPI == 0) {
#pragma unroll
                for (int r = 0; r < 4; ++r)
                    ((float*)O0)[(size_t)(row0 + r) * N + col] = acc[mt][nt][r];
            } else if (EPI == 1) {
#pragma unroll
                for (int r = 0; r < 4; ++r) {
                    float v = acc[mt][nt][r];
                    unsigned short h = f2h(v);
                    ((unsigned short*)O0)[(size_t)(row0 + r) * N + col] = h;
                    ((unsigned short*)O1)[(size_t)(row0 + r) * N + col] =
                        f2h(v - h2f(h));
                }
            } else if (EPI == 2) {
#pragma unroll
                for (int r = 0; r < 4; ++r)
                    ((unsigned short*)O0)[(size_t)(row0 + r) * N + col] =
                        f2h(acc[mt][nt][r]);
            } else {  // EPI == 3: Vt[b][h][d][s]; regs are consecutive s
                const int b = row0 >> 11, s = row0 & 2047;
                const int hh = col >> 6, d = col & 63;
                unsigned short vs[4];
#pragma unroll
                for (int r = 0; r < 4; ++r) vs[r] = f2h(acc[mt][nt][r]);
                *(ushort4*)((unsigned short*)O0 +
                            (((size_t)(b * HEADS + hh)) * HD + d) * SEQ + s) =
                    *(ushort4*)vs;
            }
        }
}

// ---------------------------------------------------------------------------
// 32x32x16 MFMA flash attention (S^T formulation, LDS-minimal).
// Block = (b, h, 128-row Q tile), 4 waves, wave owns 32 q-rows.
// S^T = K.Q^T via mfma_32x32x16 (A=K from LDS, B=Q hoisted): C/D col=lane&31
// = q-row -> softmax per LANE (in-lane 32-reg reduce + one shfl_xor(32)).
// 3-pass split QK^T (Kh.Qh + Kl.Qh + Kh.Ql) for fp32-grade logits (log2 units,
// QSCALE folded into Wq). P converts C-layout -> PV operand layout IN
// REGISTERS (cvt_pkrtz + shfl_xor(32) reg-quad swap) - no P LDS round-trip.
// PV: O^T = V^T.P^T (A=V^T straight from d-major Vs tile; C col = q-row ->
// per-lane l normalization, 8B-packed stores).
// LDS 36.9 KB (Q staging region aliased by K/Kl/V tiles after hoist).
// ---------------------------------------------------------------------------
__global__ __launch_bounds__(256, 3) void attn_f16(
    const unsigned short* __restrict__ QKh,   // [M_TOK][2048]: Q | K  (hi)
    const unsigned short* __restrict__ QKl,   // [M_TOK][2048]: Q | K  (lo)
    const unsigned short* __restrict__ Vt,    // [b][h][d][s]
    unsigned short* __restrict__ Oc)          // [b][s][h*64+d] f16
{
    __shared__ unsigned short SM[18432];      // 36,864 B
    unsigned short* Qh_s = SM;                // [128][72] (init only)
    unsigned short* Ql_s = SM + 9216;         // [128][72] (init only)
    unsigned short* Ks   = SM;                // [64][72]  Kh   (loop)
    unsigned short* Ksl  = SM + 4608;         // [64][72]  Kl   (loop)
    unsigned short* Vs   = SM + 9216;         // [64][72]  V^T  (loop)

    const int t = threadIdx.x;
    const int w = t >> 6, lane = t & 63;
    const int g = lane >> 5, l31 = lane & 31;
    const int b = blockIdx.z, h = blockIdx.y, q0 = blockIdx.x * 128;

    const size_t row0   = (size_t)b * SEQ;
    const size_t qcol   = (size_t)h * HD;          // Q cols [h*64, h*64+64)
    const size_t kcol   = 1024 + qcol;             // K cols
    const size_t vtbase = ((size_t)(b * HEADS + h)) * HD * SEQ;

    {   // stage Q tile: 128 rows x 64 f16, hi+lo, pitch 72
        const int sr = t >> 1, sc = (t & 1) * 32;
        const size_t gq = (row0 + q0 + sr) * QK_LD + qcol + sc;
#pragma unroll
        for (int c = 0; c < 32; c += 8) {
            *(float4*)&Qh_s[sr * 72 + sc + c] = *(const float4*)(QKh + gq + c);
            *(float4*)&Ql_s[sr * 72 + sc + c] = *(const float4*)(QKl + gq + c);
        }
    }
    __syncthreads();

    // Hoist Q B-frags: lane n = q-row = w*32+l31, k(d) = ks*16 + g*8 + j.
    half8 bQh[4], bQl[4];
    {
        const int qr = (w * 32 + l31) * 72;
#pragma unroll
        for (int ks = 0; ks < 4; ++ks) {
            bQh[ks] = *(const half8*)&Qh_s[qr + ks * 16 + g * 8];
            bQl[ks] = *(const half8*)&Ql_s[qr + ks * 16 + g * 8];
        }
    }

    f32x16 o_acc[2];
#pragma unroll
    for (int mt = 0; mt < 2; ++mt)
#pragma unroll
        for (int r = 0; r < 16; ++r) o_acc[mt][r] = 0.f;
    float m_r = -3.0e38f, l_r = 0.f;

    const int sr = t >> 2, sc = (t & 3) * 16;   // loop staging: 64 x 64

    for (int k0 = 0; k0 < SEQ; k0 += 64) {
        __syncthreads();  // prior-iter frag reads (and Q hoist at iter 0) done
        {
            const size_t gk = (row0 + k0 + sr) * QK_LD + kcol + sc;
            *(float4*)&Ks [sr * 72 + sc]     = *(const float4*)(QKh + gk);
            *(float4*)&Ks [sr * 72 + sc + 8] = *(const float4*)(QKh + gk + 8);
            *(float4*)&Ksl[sr * 72 + sc]     = *(const float4*)(QKl + gk);
            *(float4*)&Ksl[sr * 72 + sc + 8] = *(const float4*)(QKl + gk + 8);
            const size_t gv = vtbase + (size_t)sr * SEQ + k0 + sc;
            *(float4*)&Vs[sr * 72 + sc]      = *(const float4*)(Vt + gv);
            *(float4*)&Vs[sr * 72 + sc + 8]  = *(const float4*)(Vt + gv + 8);
        }
        __syncthreads();

        // S^T = K.Q^T: M = 64 keys (2 tiles), N = 32 q-rows, k = d (4 steps)
        f32x16 s[2];
#pragma unroll
        for (int kt = 0; kt < 2; ++kt)
#pragma unroll
            for (int r = 0; r < 16; ++r) s[kt][r] = 0.f;
#pragma unroll
        for (int kt = 0; kt < 2; ++kt)
#pragma unroll
            for (int ks = 0; ks < 4; ++ks) {
                const int aro = (kt * 32 + l31) * 72 + ks * 16 + g * 8;
                half8 aKh = *(const half8*)&Ks[aro];
                half8 aKl = *(const half8*)&Ksl[aro];
                s[kt] = __builtin_amdgcn_mfma_f32_32x32x16_f16(
                    aKh, bQh[ks], s[kt], 0, 0, 0);
                s[kt] = __builtin_amdgcn_mfma_f32_32x32x16_f16(
                    aKl, bQh[ks], s[kt], 0, 0, 0);
                s[kt] = __builtin_amdgcn_mfma_f32_32x32x16_f16(
                    aKh, bQl[ks], s[kt], 0, 0, 0);
            }

        // Per-lane online softmax (lane's q-row = w*32+l31; holds 32/64 keys)
        float mx = s[0][0];
#pragma unroll
        for (int kt = 0; kt < 2; ++kt)
#pragma unroll
            for (int r = 0; r < 16; ++r) mx = fmaxf(mx, s[kt][r]);
        mx = fmaxf(mx, __shfl_xor(mx, 32));
        const float nm = fmaxf(m_r, mx);
        const float al = fast_exp2(m_r - nm);
        m_r = nm;
        float rs = 0.f;
#pragma unroll
        for (int kt = 0; kt < 2; ++kt)
#pragma unroll
            for (int r = 0; r < 16; ++r) {
                float pv = fast_exp2(s[kt][r] - nm);
                s[kt][r] = pv;
                rs += pv;
            }
        rs += __shfl_xor(rs, 32);
        l_r = l_r * al + rs;
#pragma unroll
        for (int mt = 0; mt < 2; ++mt)
#pragma unroll
            for (int r = 0; r < 16; ++r) o_acc[mt][r] *= al;

        // P: C-layout -> PV operand layout, in registers.
        // Lane holds keys (r&3)+8*(r>>2)+4g per keytile; operand needs
        // keys 8g+j per 16-key kstep: swap one reg-quad with lane^32.
        half8 bP[4];
#pragma unroll
        for (int kt = 0; kt < 2; ++kt)
#pragma unroll
            for (int ksl = 0; ksl < 2; ++ksl) {
                const int base = ksl * 8;
                unsigned int lo0 = pk2(s[kt][base + 0], s[kt][base + 1]);
                unsigned int lo1 = pk2(s[kt][base + 2], s[kt][base + 3]);
                unsigned int hi0 = pk2(s[kt][base + 4], s[kt][base + 5]);
                unsigned int hi1 = pk2(s[kt][base + 6], s[kt][base + 7]);
                unsigned int s0 = g ? lo0 : hi0;   // g=0 sends high, g=1 low
                unsigned int s1 = g ? lo1 : hi1;
                unsigned int r0 = (unsigned int)__shfl_xor((int)s0, 32);
                unsigned int r1 = (unsigned int)__shfl_xor((int)s1, 32);
                union { unsigned int u[4]; half8 hv; } u;
                u.u[0] = g ? r0 : lo0;
                u.u[1] = g ? r1 : lo1;
                u.u[2] = g ? hi0 : r0;
                u.u[3] = g ? hi1 : r1;
                bP[kt * 2 + ksl] = u.hv;
            }

        // O^T += V^T . P^T : M = d (2 tiles), N = q, k = key (4 steps)
#pragma unroll
        for (int mt = 0; mt < 2; ++mt)
#pragma unroll
            for (int kk = 0; kk < 4; ++kk) {
                half8 aV = *(const half8*)&Vs[(mt * 32 + l31) * 72 +
                                              kk * 16 + g * 8];
                o_acc[mt] = __builtin_amdgcn_mfma_f32_32x32x16_f16(
                    aV, bP[kk], o_acc[mt], 0, 0, 0);
            }
    }

    // Epilogue: O^T col = own q-row; rows d = (r&3)+8*(r>>2)+4g+32mt.
    // Normalize by per-lane l; pack 4 consecutive d per 8B store.
    const float inv = 1.0f / l_r;
    unsigned short* orow = Oc + (row0 + q0 + w * 32 + l31) * DM + h * HD;
#pragma unroll
    for (int mt = 0; mt < 2; ++mt)
#pragma unroll
        for (int rq = 0; rq < 4; ++rq) {
            unsigned int w0 = pk2(o_acc[mt][rq * 4 + 0] * inv,
                                  o_acc[mt][rq * 4 + 1] * inv);
            unsigned int w1 = pk2(o_acc[mt][rq * 4 + 2] * inv,
                                  o_acc[mt][rq * 4 + 3] * inv);
            const int d0 = mt * 32 + rq * 8 + g * 4;
            uint2 pkd; pkd.x = w0; pkd.y = w1;
            *(uint2*)(orow + d0) = pkd;
        }
}

// ---------------------------------------------------------------------------
extern "C" void kernel_launch(void* const* d_in, const int* in_sizes, int n_in,
                              void* d_out, int out_size, void* d_ws, size_t ws_size,
                              hipStream_t stream) {
    const float* x  = (const float*)d_in[0];
    const float* Wq = (const float*)d_in[1];
    const float* Wk = (const float*)d_in[2];
    const float* Wv = (const float*)d_in[3];
    const float* Wo = (const float*)d_in[4];
    float* out = (float*)d_out;

    char* ws = (char*)d_ws;
    const size_t SZ_TOK = (size_t)M_TOK * DM * 2;  // 16 MB f16 token matrix
    const size_t SZ_W   = (size_t)DM * DM * 2;     // 2 MB

    unsigned short* xh     = (unsigned short*)(ws);
    unsigned short* xl     = (unsigned short*)(ws + SZ_TOK);
    unsigned short* Wqkt_h = (unsigned short*)(ws + 2 * SZ_TOK);            // 4 MB
    unsigned short* Wqkt_l = (unsigned short*)(ws + 2 * SZ_TOK + 2 * SZ_W); // 4 MB
    unsigned short* Wvt    = (unsigned short*)(ws + 2 * SZ_TOK + 4 * SZ_W);
    unsigned short* Wot    = (unsigned short*)(ws + 2 * SZ_TOK + 5 * SZ_W);
    unsigned short* QKh    = (unsigned short*)(ws + 2 * SZ_TOK + 6 * SZ_W); // 32 MB
    unsigned short* QKl    = (unsigned short*)(ws + 4 * SZ_TOK + 6 * SZ_W); // 32 MB
    unsigned short* Vt_    = (unsigned short*)(ws + 6 * SZ_TOK + 6 * SZ_W); // 16 MB
    unsigned short* concat = xh;  // x dead after V projection

    dim3 blk(256);

    hipLaunchKernelGGL(split_cast, dim3(M_TOK * DM / (256 * 8)), blk, 0, stream,
                       x, xh, xl);
    dim3 wgrid(DM / 64, DM / 64);
    hipLaunchKernelGGL((wtrans<1>), wgrid, blk, 0, stream, Wq, Wqkt_h, Wqkt_l,
                       QSCALE);
    hipLaunchKernelGGL((wtrans<1>), wgrid, blk, 0, stream, Wk,
                       Wqkt_h + (size_t)DM * DM, Wqkt_l + (size_t)DM * DM, 1.0f);
    hipLaunchKernelGGL((wtrans<0>), wgrid, blk, 0, stream, Wv, Wvt, nullptr, 1.0f);
    hipLaunchKernelGGL((wtrans<0>), wgrid, blk, 0, stream, Wo, Wot, nullptr, 1.0f);

    // Merged Q|K projection: N = 2048, 3-pass split in, split out.
    dim3 gqk(QK_LD / 128, M_TOK / 128);   // 16 x 64
    hipLaunchKernelGGL((gemm_f16<3, 1>), gqk, blk, 0, stream,
                       xh, xl, Wqkt_h, Wqkt_l, QKh, QKl, M_TOK, QK_LD, DM);
    dim3 ggrid(DM / 128, M_TOK / 128);    // 8 x 64
    hipLaunchKernelGGL((gemm_f16<1, 3>), ggrid, blk, 0, stream,
                       xh, nullptr, Wvt, nullptr, Vt_, nullptr, M_TOK, DM, DM);

    dim3 agrid(SEQ / 128, HEADS, BATCH);  // 16 x 16 x 4 = 1024 blocks
    hipLaunchKernelGGL(attn_f16, agrid, blk, 0, stream, QKh, QKl, Vt_, concat);

    hipLaunchKernelGGL((gemm_f16<1, 0>), ggrid, blk, 0, stream,
                       concat, nullptr, Wot, nullptr, out, nullptr, M_TOK, DM, DM);
}

// Round 7
// 433.038 us; speedup vs baseline: 4.8003x; 1.1220x over previous
//
#include <hip/hip_runtime.h>
#include <hip/hip_fp16.h>

#define BATCH   4
#define SEQ     2048
#define DM      1024
#define HEADS   16
#define HD      64
#define M_TOK   (BATCH * SEQ)   // 8192
#define QK_LD   2048            // merged Q|K projection leading dim

// 0.125 (1/sqrt(64)) * log2(e): folded into Wq so logits come out in log2 units.
#define QSCALE  0.1803368801111204f

typedef __attribute__((ext_vector_type(8)))  _Float16 half8;
typedef __attribute__((ext_vector_type(4)))  float    f32x4;
typedef __attribute__((ext_vector_type(16))) float    f32x16;

__device__ __forceinline__ unsigned short f2h(float x) {
    return __half_as_ushort(__float2half(x));
}
__device__ __forceinline__ float h2f(unsigned short u) {
    return __half2float(__ushort_as_half(u));
}
// v_exp_f32 IS exp2 on gfx9xx.
__device__ __forceinline__ float fast_exp2(float x) {
    float r; asm volatile("v_exp_f32 %0, %1" : "=v"(r) : "v"(x)); return r;
}
// pack two f32 -> f16x2 in one VGPR (v_cvt_pkrtz_f16_f32), a in [15:0].
__device__ __forceinline__ unsigned int pk2(float a, float b) {
    __fp16 __attribute__((ext_vector_type(2))) h =
        __builtin_amdgcn_cvt_pkrtz(a, b);
    return __builtin_bit_cast(unsigned int, h);
}
// async global->LDS DMA, 16B per lane; LDS dest = uniform base + lane*16.
__device__ __forceinline__ void dma16(const void* g, void* l) {
    __builtin_amdgcn_global_load_lds(
        (const __attribute__((address_space(1))) void*)g,
        (__attribute__((address_space(3))) void*)l, 16, 0, 0);
}

// ---------------------------------------------------------------------------
// x -> hi/lo f16 split (elementwise)
// ---------------------------------------------------------------------------
__global__ __launch_bounds__(256) void split_cast(
    const float* __restrict__ x, unsigned short* __restrict__ hi,
    unsigned short* __restrict__ lo)
{
    const int i = (blockIdx.x * 256 + threadIdx.x) * 8;
    float4 a = *(const float4*)(x + i);
    float4 b = *(const float4*)(x + i + 4);
    float v[8] = {a.x, a.y, a.z, a.w, b.x, b.y, b.z, b.w};
    unsigned short hb[8], lb[8];
#pragma unroll
    for (int j = 0; j < 8; ++j) {
        hb[j] = f2h(v[j]);
        lb[j] = f2h(v[j] - h2f(hb[j]));
    }
    *(float4*)(hi + i) = *(float4*)hb;
    *(float4*)(lo + i) = *(float4*)lb;
}

// ---------------------------------------------------------------------------
// Weight transpose (+scale, +optional split): W[K][N] f32 -> Wt[N][K] f16
// ---------------------------------------------------------------------------
template<int SPLIT>
__global__ __launch_bounds__(256) void wtrans(
    const float* __restrict__ W, unsigned short* __restrict__ Th_out,
    unsigned short* __restrict__ Tl_out, float scale)
{
    __shared__ unsigned short Th[64][72];
    __shared__ unsigned short Tl[SPLIT ? 64 : 1][72];
    const int t  = threadIdx.x;
    const int n0 = blockIdx.x * 64, k0 = blockIdx.y * 64;
    const int kr = t >> 2, cg = (t & 3) << 4;
#pragma unroll
    for (int jj = 0; jj < 16; jj += 4) {
        float4 wv = *(const float4*)(W + (size_t)(k0 + kr) * DM + n0 + cg + jj);
        float vv[4] = {wv.x, wv.y, wv.z, wv.w};
#pragma unroll
        for (int j = 0; j < 4; ++j) {
            float v = vv[j] * scale;
            unsigned short h = f2h(v);
            Th[cg + jj + j][kr] = h;
            if (SPLIT) Tl[cg + jj + j][kr] = f2h(v - h2f(h));
        }
    }
    __syncthreads();
    const int nr = t >> 2, kg = (t & 3) << 4;
    size_t go = (size_t)(n0 + nr) * DM + k0 + kg;
    *(float4*)(Th_out + go)     = *(float4*)&Th[nr][kg];
    *(float4*)(Th_out + go + 8) = *(float4*)&Th[nr][kg + 8];
    if (SPLIT) {
        *(float4*)(Tl_out + go)     = *(float4*)&Tl[nr][kg];
        *(float4*)(Tl_out + go + 8) = *(float4*)&Tl[nr][kg + 8];
    }
}

// ---------------------------------------------------------------------------
// f16 MFMA GEMM: C = A[M,K] @ Bt[N,K]^T, 128x128 tile, BK=32.
// ASYNC PIPELINE: double-buffered LDS, ONE barrier per iter; the barrier's
// vmcnt(0) drain IS the wait for the prefetch issued a full compute-phase
// earlier (iter it stages it+1 right after the barrier, then computes it).
// PASSES: 1 = plain; 3 = hi/lo split (A*B + A*Bl + Al*B) fp32-grade.
// EPI: 0 = f32 out; 1 = split-f16 out; 2 = f16 out; 3 = transposed-V f16.
// ---------------------------------------------------------------------------
template<int PASSES, int EPI>
__global__ __launch_bounds__(256, 2) void gemm_f16(
    const unsigned short* __restrict__ Ah, const unsigned short* __restrict__ Al,
    const unsigned short* __restrict__ Bh, const unsigned short* __restrict__ Bl,
    void* __restrict__ O0, void* __restrict__ O1, int M, int N, int K)
{
    __shared__ unsigned short As_h[2][128 * 32];
    __shared__ unsigned short Bs_h[2][128 * 32];
    __shared__ unsigned short As_l[PASSES == 3 ? 2 : 1][PASSES == 3 ? 128 * 32 : 16];
    __shared__ unsigned short Bs_l[PASSES == 3 ? 2 : 1][PASSES == 3 ? 128 * 32 : 16];

    const int t = threadIdx.x;
    const int w = t >> 6, lane = t & 63, quad = lane >> 4, l15 = lane & 15;
    const int wm = w >> 1, wn = w & 1;
    const int m0 = blockIdx.y * 128, n0 = blockIdx.x * 128;

    const int drow = w * 32 + (lane >> 2);
    const int dcol = (lane & 3) * 8;

    auto stage = [&](int buf, int k0) {
#pragma unroll
        for (int inst = 0; inst < 2; ++inst) {
            const size_t ga = (size_t)(m0 + drow + inst * 16) * K + k0 + dcol;
            const size_t gb = (size_t)(n0 + drow + inst * 16) * K + k0 + dcol;
            const int lo = (w * 32 + inst * 16) * 32;
            dma16(Ah + ga, &As_h[buf][lo]);
            dma16(Bh + gb, &Bs_h[buf][lo]);
            if (PASSES == 3) {
                dma16(Al + ga, &As_l[buf][lo]);
                dma16(Bl + gb, &Bs_l[buf][lo]);
            }
        }
    };

    f32x4 acc[4][4];
#pragma unroll
    for (int mt = 0; mt < 4; ++mt)
#pragma unroll
        for (int nt = 0; nt < 4; ++nt)
#pragma unroll
            for (int r = 0; r < 4; ++r) acc[mt][nt][r] = 0.f;

    const int NIT = K >> 5;
    stage(0, 0);
    for (int it = 0; it < NIT; ++it) {
        __syncthreads();   // drains vmcnt -> buf[cur] ready; prior cur^1 reads done
        const int cur = it & 1;
        if (it + 1 < NIT) stage(cur ^ 1, (it + 1) * 32);

        half8 aH[4], bH[4], aL[4], bL[4];
#pragma unroll
        for (int mt = 0; mt < 4; ++mt) {
            const int row = wm * 64 + mt * 16 + l15;
            aH[mt] = *(const half8*)&As_h[cur][row * 32 + quad * 8];
            if (PASSES == 3) aL[mt] = *(const half8*)&As_l[cur][row * 32 + quad * 8];
        }
#pragma unroll
        for (int nt = 0; nt < 4; ++nt) {
            const int row = wn * 64 + nt * 16 + l15;
            bH[nt] = *(const half8*)&Bs_h[cur][row * 32 + quad * 8];
            if (PASSES == 3) bL[nt] = *(const half8*)&Bs_l[cur][row * 32 + quad * 8];
        }
#pragma unroll
        for (int mt = 0; mt < 4; ++mt)
#pragma unroll
            for (int nt = 0; nt < 4; ++nt) {
                acc[mt][nt] = __builtin_amdgcn_mfma_f32_16x16x32_f16(
                    aH[mt], bH[nt], acc[mt][nt], 0, 0, 0);
                if (PASSES == 3) {
                    acc[mt][nt] = __builtin_amdgcn_mfma_f32_16x16x32_f16(
                        aH[mt], bL[nt], acc[mt][nt], 0, 0, 0);
                    acc[mt][nt] = __builtin_amdgcn_mfma_f32_16x16x32_f16(
                        aL[mt], bH[nt], acc[mt][nt], 0, 0, 0);
                }
            }
    }

    // Epilogue. C/D layout: col = lane&15, row = quad*4 + reg.
#pragma unroll
    for (int mt = 0; mt < 4; ++mt)
#pragma unroll
        for (int nt = 0; nt < 4; ++nt) {
            const int row0 = m0 + wm * 64 + mt * 16 + quad * 4;
            const int col  = n0 + wn * 64 + nt * 16 + l15;
            if (EPI == 0) {
#pragma unroll
                for (int r = 0; r < 4; ++r)
                    ((float*)O0)[(size_t)(row0 + r) * N + col] = acc[mt][nt][r];
            } else if (EPI == 1) {
#pragma unroll
                for (int r = 0; r < 4; ++r) {
                    float v = acc[mt][nt][r];
                    unsigned short h = f2h(v);
                    ((unsigned short*)O0)[(size_t)(row0 + r) * N + col] = h;
                    ((unsigned short*)O1)[(size_t)(row0 + r) * N + col] =
                        f2h(v - h2f(h));
                }
            } else if (EPI == 2) {
#pragma unroll
                for (int r = 0; r < 4; ++r)
                    ((unsigned short*)O0)[(size_t)(row0 + r) * N + col] =
                        f2h(acc[mt][nt][r]);
            } else {  // EPI == 3: Vt[b][h][d][s]; regs are consecutive s
                const int b = row0 >> 11, s = row0 & 2047;
                const int hh = col >> 6, d = col & 63;
                unsigned short vs[4];
#pragma unroll
                for (int r = 0; r < 4; ++r) vs[r] = f2h(acc[mt][nt][r]);
                *(ushort4*)((unsigned short*)O0 +
                            (((size_t)(b * HEADS + hh)) * HD + d) * SEQ + s) =
                    *(ushort4*)vs;
            }
        }
}

// ---------------------------------------------------------------------------
// 32x32x16 MFMA flash attention, async-pipelined.
// Block = (b, h, 256-row Q tile), 4 waves; wave owns 2 q-sets of 32 rows
// (q = q0 + qs*128 + w*32 + l31) -> K/V A-frags amortize over 2x MFMA.
// Q B-frags loaded DIRECTLY global->VGPR (no LDS staging). K(hi,lo) and V^T
// tiles double-buffered in LDS via global_load_lds with XOR swizzle
// (chunk ^= row&7) on unpadded [64][64] tiles: DMA dest is lane-contiguous,
// frag reads cover all 32 banks per 8-lane group (conflict-free).
// ONE barrier per iter: barrier drains the prefetch issued last iter, then
// next prefetch is issued, then compute (S^T 3-pass split, per-lane online
// softmax in log2 units, in-register P transform, PV as O^T = V^T.P^T).
// LDS 48 KB -> 2 blocks/CU (grid 512 = exactly 2/CU).
// ---------------------------------------------------------------------------
__global__ __launch_bounds__(256, 2) void attn_f16(
    const unsigned short* __restrict__ QKh,   // [M_TOK][2048]: Q | K  (hi)
    const unsigned short* __restrict__ QKl,   // [M_TOK][2048]: Q | K  (lo)
    const unsigned short* __restrict__ Vt,    // [b][h][d][s]
    unsigned short* __restrict__ Oc)          // [b][s][h*64+d] f16
{
    __shared__ unsigned short SM[2][3 * 4096];  // per buf: Kh | Kl | V^T, 8 KB each

    const int t = threadIdx.x;
    const int w = t >> 6, lane = t & 63;
    const int g = lane >> 5, l31 = lane & 31;
    const int b = blockIdx.z, h = blockIdx.y, q0 = blockIdx.x * 256;

    const size_t row0   = (size_t)b * SEQ;
    const size_t qcol   = (size_t)h * HD;          // Q cols [h*64, h*64+64)
    const size_t kcol   = 1024 + qcol;             // K cols
    const size_t vtbase = ((size_t)(b * HEADS + h)) * HD * SEQ;

    // DMA per-lane invariants: lane l -> row_local = l>>3, swizzled chunk.
    const int rl  = lane >> 3;                       // 0..7
    const int sw8 = ((lane & 7) ^ (rl & 7)) * 8;     // element offset in row
    const int x7  = l31 & 7;                         // frag-read swizzle key

    auto stage = [&](int buf, int k0) {
#pragma unroll
        for (int inst = 0; inst < 2; ++inst) {
            const int r8 = w * 16 + inst * 8;        // first of 8 rows
            const size_t gk = (row0 + k0 + r8 + rl) * QK_LD + kcol + sw8;
            const int lo = r8 * 64;
            dma16(QKh + gk, &SM[buf][lo]);
            dma16(QKl + gk, &SM[buf][4096 + lo]);
            const size_t gv = vtbase + (size_t)(r8 + rl) * SEQ + k0 + sw8;
            dma16(Vt + gv, &SM[buf][8192 + lo]);
        }
    };

    // Q B-frags direct from global: lane n = q-row, k(d) = ks*16 + g*8 + j.
    half8 bQh[2][4], bQl[2][4];
#pragma unroll
    for (int qs = 0; qs < 2; ++qs) {
        const size_t qr = (row0 + q0 + qs * 128 + w * 32 + l31) * QK_LD + qcol;
#pragma unroll
        for (int ks = 0; ks < 4; ++ks) {
            bQh[qs][ks] = *(const half8*)(QKh + qr + ks * 16 + g * 8);
            bQl[qs][ks] = *(const half8*)(QKl + qr + ks * 16 + g * 8);
        }
    }

    f32x16 o_acc[2][2];
#pragma unroll
    for (int qs = 0; qs < 2; ++qs)
#pragma unroll
        for (int mt = 0; mt < 2; ++mt)
#pragma unroll
            for (int r = 0; r < 16; ++r) o_acc[qs][mt][r] = 0.f;
    float m_r[2] = {-3.0e38f, -3.0e38f}, l_r[2] = {0.f, 0.f};

    stage(0, 0);
    const int NIT = SEQ / 64;
    for (int it = 0; it < NIT; ++it) {
        __syncthreads();   // drains vmcnt -> buf[cur] ready; cur^1 reads done
        const int cur = it & 1;
        if (it + 1 < NIT) stage(cur ^ 1, (it + 1) * 64);
        const unsigned short* Ks  = &SM[cur][0];
        const unsigned short* Ksl = &SM[cur][4096];
        const unsigned short* Vs  = &SM[cur][8192];

        // S^T = K.Q^T: M = 64 keys (2 tiles), k = d (4 steps), 3-pass split
        f32x16 s[2][2];
#pragma unroll
        for (int qs = 0; qs < 2; ++qs)
#pragma unroll
            for (int kt = 0; kt < 2; ++kt)
#pragma unroll
                for (int r = 0; r < 16; ++r) s[qs][kt][r] = 0.f;
#pragma unroll
        for (int kt = 0; kt < 2; ++kt)
#pragma unroll
            for (int ks = 0; ks < 4; ++ks) {
                const int off = (kt * 32 + l31) * 64 + (((ks * 2 + g) ^ x7) * 8);
                half8 aKh = *(const half8*)&Ks[off];
                half8 aKl = *(const half8*)&Ksl[off];
#pragma unroll
                for (int qs = 0; qs < 2; ++qs) {
                    s[qs][kt] = __builtin_amdgcn_mfma_f32_32x32x16_f16(
                        aKh, bQh[qs][ks], s[qs][kt], 0, 0, 0);
                    s[qs][kt] = __builtin_amdgcn_mfma_f32_32x32x16_f16(
                        aKl, bQh[qs][ks], s[qs][kt], 0, 0, 0);
                    s[qs][kt] = __builtin_amdgcn_mfma_f32_32x32x16_f16(
                        aKh, bQl[qs][ks], s[qs][kt], 0, 0, 0);
                }
            }

        half8 bP[2][4];
#pragma unroll
        for (int qs = 0; qs < 2; ++qs) {
            // Per-lane online softmax (lane's q-row; holds 32 of 64 keys)
            float mx = s[qs][0][0];
#pragma unroll
            for (int kt = 0; kt < 2; ++kt)
#pragma unroll
                for (int r = 0; r < 16; ++r) mx = fmaxf(mx, s[qs][kt][r]);
            mx = fmaxf(mx, __shfl_xor(mx, 32));
            const float nm = fmaxf(m_r[qs], mx);
            const float al = fast_exp2(m_r[qs] - nm);
            m_r[qs] = nm;
            float rs = 0.f;
#pragma unroll
            for (int kt = 0; kt < 2; ++kt)
#pragma unroll
                for (int r = 0; r < 16; ++r) {
                    float pv = fast_exp2(s[qs][kt][r] - nm);
                    s[qs][kt][r] = pv;
                    rs += pv;
                }
            rs += __shfl_xor(rs, 32);
            l_r[qs] = l_r[qs] * al + rs;
#pragma unroll
            for (int mt = 0; mt < 2; ++mt)
#pragma unroll
                for (int r = 0; r < 16; ++r) o_acc[qs][mt][r] *= al;

            // P: C-layout -> PV operand layout, in registers (reg-quad swap
            // between lane pairs l <-> l^32).
#pragma unroll
            for (int kt = 0; kt < 2; ++kt)
#pragma unroll
                for (int ksl = 0; ksl < 2; ++ksl) {
                    const int base = ksl * 8;
                    unsigned int lo0 = pk2(s[qs][kt][base + 0], s[qs][kt][base + 1]);
                    unsigned int lo1 = pk2(s[qs][kt][base + 2], s[qs][kt][base + 3]);
                    unsigned int hi0 = pk2(s[qs][kt][base + 4], s[qs][kt][base + 5]);
                    unsigned int hi1 = pk2(s[qs][kt][base + 6], s[qs][kt][base + 7]);
                    unsigned int s0 = g ? lo0 : hi0;
                    unsigned int s1 = g ? lo1 : hi1;
                    unsigned int r0 = (unsigned int)__shfl_xor((int)s0, 32);
                    unsigned int r1 = (unsigned int)__shfl_xor((int)s1, 32);
                    union { unsigned int u[4]; half8 hv; } u;
                    u.u[0] = g ? r0 : lo0;
                    u.u[1] = g ? r1 : lo1;
                    u.u[2] = g ? hi0 : r0;
                    u.u[3] = g ? hi1 : r1;
                    bP[qs][kt * 2 + ksl] = u.hv;
                }
        }

        // O^T += V^T . P^T : M = d (2 tiles), k = key (4 steps)
#pragma unroll
        for (int mt = 0; mt < 2; ++mt)
#pragma unroll
            for (int kk = 0; kk < 4; ++kk) {
                const int off = (mt * 32 + l31) * 64 + (((kk * 2 + g) ^ x7) * 8);
                half8 aV = *(const half8*)&Vs[off];
#pragma unroll
                for (int qs = 0; qs < 2; ++qs)
                    o_acc[qs][mt] = __builtin_amdgcn_mfma_f32_32x32x16_f16(
                        aV, bP[qs][kk], o_acc[qs][mt], 0, 0, 0);
            }
    }

    // Epilogue: O^T col = own q-row; rows d = (r&3)+8*(r>>2)+4g+32mt.
#pragma unroll
    for (int qs = 0; qs < 2; ++qs) {
        const float inv = 1.0f / l_r[qs];
        unsigned short* orow =
            Oc + (row0 + q0 + qs * 128 + w * 32 + l31) * DM + h * HD;
#pragma unroll
        for (int mt = 0; mt < 2; ++mt)
#pragma unroll
            for (int rq = 0; rq < 4; ++rq) {
                unsigned int w0 = pk2(o_acc[qs][mt][rq * 4 + 0] * inv,
                                      o_acc[qs][mt][rq * 4 + 1] * inv);
                unsigned int w1 = pk2(o_acc[qs][mt][rq * 4 + 2] * inv,
                                      o_acc[qs][mt][rq * 4 + 3] * inv);
                const int d0 = mt * 32 + rq * 8 + g * 4;
                uint2 pkd; pkd.x = w0; pkd.y = w1;
                *(uint2*)(orow + d0) = pkd;
            }
    }
}

// ---------------------------------------------------------------------------
extern "C" void kernel_launch(void* const* d_in, const int* in_sizes, int n_in,
                              void* d_out, int out_size, void* d_ws, size_t ws_size,
                              hipStream_t stream) {
    const float* x  = (const float*)d_in[0];
    const float* Wq = (const float*)d_in[1];
    const float* Wk = (const float*)d_in[2];
    const float* Wv = (const float*)d_in[3];
    const float* Wo = (const float*)d_in[4];
    float* out = (float*)d_out;

    char* ws = (char*)d_ws;
    const size_t SZ_TOK = (size_t)M_TOK * DM * 2;  // 16 MB f16 token matrix
    const size_t SZ_W   = (size_t)DM * DM * 2;     // 2 MB

    unsigned short* xh     = (unsigned short*)(ws);
    unsigned short* xl     = (unsigned short*)(ws + SZ_TOK);
    unsigned short* Wqkt_h = (unsigned short*)(ws + 2 * SZ_TOK);            // 4 MB
    unsigned short* Wqkt_l = (unsigned short*)(ws + 2 * SZ_TOK + 2 * SZ_W); // 4 MB
    unsigned short* Wvt    = (unsigned short*)(ws + 2 * SZ_TOK + 4 * SZ_W);
    unsigned short* Wot    = (unsigned short*)(ws + 2 * SZ_TOK + 5 * SZ_W);
    unsigned short* QKh    = (unsigned short*)(ws + 2 * SZ_TOK + 6 * SZ_W); // 32 MB
    unsigned short* QKl    = (unsigned short*)(ws + 4 * SZ_TOK + 6 * SZ_W); // 32 MB
    unsigned short* Vt_    = (unsigned short*)(ws + 6 * SZ_TOK + 6 * SZ_W); // 16 MB
    unsigned short* concat = xh;  // x dead after V projection

    dim3 blk(256);

    hipLaunchKernelGGL(split_cast, dim3(M_TOK * DM / (256 * 8)), blk, 0, stream,
                       x, xh, xl);
    dim3 wgrid(DM / 64, DM / 64);
    hipLaunchKernelGGL((wtrans<1>), wgrid, blk, 0, stream, Wq, Wqkt_h, Wqkt_l,
                       QSCALE);
    hipLaunchKernelGGL((wtrans<1>), wgrid, blk, 0, stream, Wk,
                       Wqkt_h + (size_t)DM * DM, Wqkt_l + (size_t)DM * DM, 1.0f);
    hipLaunchKernelGGL((wtrans<0>), wgrid, blk, 0, stream, Wv, Wvt, nullptr, 1.0f);
    hipLaunchKernelGGL((wtrans<0>), wgrid, blk, 0, stream, Wo, Wot, nullptr, 1.0f);

    // Merged Q|K projection: N = 2048, 3-pass split in, split out.
    dim3 gqk(QK_LD / 128, M_TOK / 128);   // 16 x 64
    hipLaunchKernelGGL((gemm_f16<3, 1>), gqk, blk, 0, stream,
                       xh, xl, Wqkt_h, Wqkt_l, QKh, QKl, M_TOK, QK_LD, DM);
    dim3 ggrid(DM / 128, M_TOK / 128);    // 8 x 64
    hipLaunchKernelGGL((gemm_f16<1, 3>), ggrid, blk, 0, stream,
                       xh, nullptr, Wvt, nullptr, Vt_, nullptr, M_TOK, DM, DM);

    dim3 agrid(SEQ / 256, HEADS, BATCH);  // 8 x 16 x 4 = 512 blocks
    hipLaunchKernelGGL(attn_f16, agrid, blk, 0, stream, QKh, QKl, Vt_, concat);

    hipLaunchKernelGGL((gemm_f16<1, 0>), ggrid, blk, 0, stream,
                       concat, nullptr, Wot, nullptr, out, nullptr, M_TOK, DM, DM);
}